// Round 9
// baseline (449.780 us; speedup 1.0000x reference)
//
#include <hip/hip_runtime.h>
#include <hip/hip_bf16.h>
#include <math.h>

// Problem dims
constexpr int NN  = 8192;
constexpr int EE  = 262144;
constexpr int IN  = 3000;
constexpr int INP = 3008;   // IN padded to mult of 64
constexpr int HID = 256;
constexpr int OUT = 64;

// Output offsets (floats) in d_out: (h2, h3, ret, ret_a, h2, h2_a)
constexpr long O_H2   = 0;
constexpr long O_H3   = 524288;          // 8192*64
constexpr long O_RET  = 25100288;        // + 8192*3000
constexpr long O_RETA = 25116672;        // + 8192*2
constexpr long O_H2B  = 25133056;        // + 8192*2
constexpr long O_H2A  = 25657344;        // + 8192*64

typedef __attribute__((ext_vector_type(8))) short short8v;   // 8 bf16 (4 VGPRs)
typedef __attribute__((ext_vector_type(4))) float f32x4;     // MFMA accumulator

__device__ __forceinline__ short f2bf(float f) {   // RNE f32 -> bf16 bits
    unsigned u = __float_as_uint(f);
    return (short)((u + 0x7FFF + ((u >> 16) & 1)) >> 16);
}
__device__ __forceinline__ float bf2f(unsigned short u) {
    return __uint_as_float(((unsigned)u) << 16);
}

// ================= conversion kernels (one-time per launch) ================================
// W1 [3000][256] -> W1t [256][3008] bf16 (transposed, k-padded)
__global__ void cvt_W1t(const float* __restrict__ W, unsigned short* __restrict__ Wt) {
    int i = blockIdx.x * 256 + threadIdx.x;            // over 256*3008
    int n = i / INP, k = i % INP;
    Wt[i] = (k < IN) ? (unsigned short)f2bf(W[(long)k * HID + n]) : 0;
}
// W2 [256][64] -> W2t [64][256] bf16
__global__ void cvt_W2t(const float* __restrict__ W, unsigned short* __restrict__ Wt) {
    int i = blockIdx.x * 256 + threadIdx.x;            // over 64*256
    int n = i / HID, k = i % HID;
    Wt[i] = (unsigned short)f2bf(W[(long)k * OUT + n]);
}
// Wd1 [64][256] -> Wd1t [256][64] bf16
__global__ void cvt_Wd1t(const float* __restrict__ W, unsigned short* __restrict__ Wt) {
    int i = blockIdx.x * 256 + threadIdx.x;            // over 256*64
    int n = i / OUT, k = i % OUT;
    Wt[i] = (unsigned short)f2bf(W[(long)k * HID + n]);
}
// Wd2 [256][3000] -> Wd2t [3072][256] bf16 (transposed, n-padded to 3072 rows)
__global__ void cvt_Wd2t(const float* __restrict__ W, unsigned short* __restrict__ Wt) {
    int i = blockIdx.x * 256 + threadIdx.x;            // over 3072*256
    int n = i / HID, k = i % HID;
    Wt[i] = (n < IN) ? (unsigned short)f2bf(W[(long)k * IN + n]) : 0;
}
// f32 -> bf16 elementwise (h2 -> h2b)
__global__ void cvt_f2b(const float* __restrict__ a, unsigned short* __restrict__ b) {
    int i = blockIdx.x * 256 + threadIdx.x;
    b[i] = (unsigned short)f2bf(a[i]);
}

// ================= 128x128 bf16 MFMA GEMM, register-prefetch ==============================
// C[M,N] = A[M,*] @ Bt[N'][ldb]^T. 4 waves (2x2), wave=64x64 (4x4 16x16x32 frags), BK=64.
// AF32=1: A is f32 (lda, valid k < aK), converted during staging. AF32=0: A bf16.
// Split-K via blockIdx.z: kbeg = z*tilesPerChunk*64; partials to Cpart[z][M][N] (no bias),
// else direct f32 to Cf (+bias), guarded c < N. Bt rows must cover gridDim.x*128 (padded).
template<int AF32>
__global__ __launch_bounds__(256) void mfma_gemm128(const void* __restrict__ Av,
                                                    const unsigned short* __restrict__ Bt,
                                                    const float* __restrict__ bias,
                                                    float* __restrict__ Cf,
                                                    float* __restrict__ Cpart,
                                                    int M, int N, int lda, int ldb, int aK,
                                                    int tilesPerChunk, int totalTiles) {
    __shared__ unsigned short As[128][72];
    __shared__ unsigned short Bs[128][72];
    int t = threadIdx.x, w = t >> 6, l = t & 63;
    int row0 = blockIdx.y * 128, col0 = blockIdx.x * 128;
    int sr = t >> 1, sh = (t & 1) * 32;     // staging row (A) / col (B), k-offset
    int wm = (w >> 1) * 64, wn = (w & 1) * 64;
    int fr = l & 15, fq = l >> 4;
    int kbeg = blockIdx.z * tilesPerChunk * 64;
    int ktiles = min(tilesPerChunk, totalTiles - blockIdx.z * tilesPerChunk);

    const float*          Af = (const float*)Av;
    const unsigned short* Ab = (const unsigned short*)Av;
    const unsigned short* Bp = Bt + (long)(col0 + sr) * ldb + sh;

    float4  paf[8];
    short8v pab[4];
    short8v pb[4];

    auto loadA = [&](int k0) {
        if (AF32) {
            const float* Ar = Af + (long)(row0 + sr) * lda + k0 + sh;
            if (k0 + 64 <= aK) {
#pragma unroll
                for (int q = 0; q < 8; ++q) paf[q] = *reinterpret_cast<const float4*>(Ar + q * 4);
            } else {
#pragma unroll
                for (int q = 0; q < 8; ++q) {
                    float4 v;
                    int kb = k0 + sh + q * 4;
                    v.x = (kb + 0 < aK) ? Ar[q * 4 + 0] : 0.f;
                    v.y = (kb + 1 < aK) ? Ar[q * 4 + 1] : 0.f;
                    v.z = (kb + 2 < aK) ? Ar[q * 4 + 2] : 0.f;
                    v.w = (kb + 3 < aK) ? Ar[q * 4 + 3] : 0.f;
                    paf[q] = v;
                }
            }
        } else {
            const unsigned short* Ar = Ab + (long)(row0 + sr) * lda + k0 + sh;
#pragma unroll
            for (int q = 0; q < 4; ++q) pab[q] = *reinterpret_cast<const short8v*>(Ar + q * 8);
        }
    };
    auto loadB = [&](int k0) {
#pragma unroll
        for (int q = 0; q < 4; ++q) pb[q] = *reinterpret_cast<const short8v*>(Bp + k0 + q * 8);
    };

    loadA(kbeg);
    loadB(kbeg);

    f32x4 acc[4][4] = {};
    for (int tt = 0; tt < ktiles; ++tt) {
        if (AF32) {
#pragma unroll
            for (int q = 0; q < 4; ++q) {
                float4 v0 = paf[q * 2], v1 = paf[q * 2 + 1];
                short8v s;
                s[0]=f2bf(v0.x); s[1]=f2bf(v0.y); s[2]=f2bf(v0.z); s[3]=f2bf(v0.w);
                s[4]=f2bf(v1.x); s[5]=f2bf(v1.y); s[6]=f2bf(v1.z); s[7]=f2bf(v1.w);
                *reinterpret_cast<short8v*>(&As[sr][sh + q * 8]) = s;
            }
        } else {
#pragma unroll
            for (int q = 0; q < 4; ++q)
                *reinterpret_cast<short8v*>(&As[sr][sh + q * 8]) = pab[q];
        }
#pragma unroll
        for (int q = 0; q < 4; ++q)
            *reinterpret_cast<short8v*>(&Bs[sr][sh + q * 8]) = pb[q];
        __syncthreads();
        if (tt + 1 < ktiles) {
            int k0 = kbeg + (tt + 1) * 64;
            loadA(k0);
            loadB(k0);
        }
#pragma unroll
        for (int kk = 0; kk < 2; ++kk) {
            short8v fa[4], fb[4];
#pragma unroll
            for (int i = 0; i < 4; ++i)
                fa[i] = *reinterpret_cast<const short8v*>(&As[wm + i * 16 + fr][kk * 32 + fq * 8]);
#pragma unroll
            for (int j = 0; j < 4; ++j)
                fb[j] = *reinterpret_cast<const short8v*>(&Bs[wn + j * 16 + fr][kk * 32 + fq * 8]);
#pragma unroll
            for (int i = 0; i < 4; ++i)
#pragma unroll
                for (int j = 0; j < 4; ++j)
                    acc[i][j] = __builtin_amdgcn_mfma_f32_16x16x32_bf16(fa[i], fb[j], acc[i][j], 0, 0, 0);
        }
        __syncthreads();
    }
    int dc = l & 15;
#pragma unroll
    for (int i = 0; i < 4; ++i)
#pragma unroll
        for (int j = 0; j < 4; ++j) {
            int c = col0 + wn + j * 16 + dc;
            if (Cpart) {
#pragma unroll
                for (int q = 0; q < 4; ++q) {
                    int r = row0 + wm + i * 16 + fq * 4 + q;
                    Cpart[((long)blockIdx.z * M + r) * N + c] = acc[i][j][q];
                }
            } else if (c < N) {
                float bb = bias ? bias[c] : 0.f;
#pragma unroll
                for (int q = 0; q < 4; ++q) {
                    int r = row0 + wm + i * 16 + fq * 4 + q;
                    Cf[(long)r * N + c] = acc[i][j][q] + bb;
                }
            }
        }
}

// sum 2 split-K partials, emit bf16 (h = feat@W1 -> h_bf)
__global__ void reduce_cvt(const float* __restrict__ p, unsigned short* __restrict__ hb) {
    int i4 = (blockIdx.x * 256 + threadIdx.x) * 4;     // over 8192*256
    float4 a = *reinterpret_cast<const float4*>(p + i4);
    float4 b = *reinterpret_cast<const float4*>(p + 2097152 + i4);
    ushort4 r;
    r.x = (unsigned short)f2bf(a.x + b.x);
    r.y = (unsigned short)f2bf(a.y + b.y);
    r.z = (unsigned short)f2bf(a.z + b.z);
    r.w = (unsigned short)f2bf(a.w + b.w);
    *reinterpret_cast<ushort4*>(hb + i4) = r;
}

// ================= 64x64 bf16 MFMA GEMM (small GEMMs: W2, Wd1) ============================
__global__ __launch_bounds__(256) void mfma_gemm_bf(const unsigned short* __restrict__ A,
                                                    const unsigned short* __restrict__ Bt,
                                                    const float* __restrict__ bias,
                                                    float* __restrict__ C,
                                                    unsigned short* __restrict__ Cb,
                                                    int M, int N, int Kp) {
    __shared__ unsigned short As[64][72];
    __shared__ unsigned short Bs[64][72];
    int t = threadIdx.x, w = t >> 6, l = t & 63;
    int row0 = blockIdx.y * 64, col0 = blockIdx.x * 64;
    int srow = t >> 2, scol = (t & 3) * 16;
    const unsigned short* Ap = A  + (long)(row0 + srow) * Kp + scol;
    const unsigned short* Bp = Bt + (long)(col0 + srow) * Kp + scol;
    int wm = (w >> 1) * 32, wn = (w & 1) * 32;
    int fr = l & 15, fq = l >> 4;
    int nk = Kp >> 6;

    short8v a0r, a1r, b0r, b1r;
    a0r = *reinterpret_cast<const short8v*>(Ap);
    a1r = *reinterpret_cast<const short8v*>(Ap + 8);
    b0r = *reinterpret_cast<const short8v*>(Bp);
    b1r = *reinterpret_cast<const short8v*>(Bp + 8);

    f32x4 acc[2][2] = {};
    for (int tt = 0; tt < nk; ++tt) {
        *reinterpret_cast<short8v*>(&As[srow][scol])     = a0r;
        *reinterpret_cast<short8v*>(&As[srow][scol + 8]) = a1r;
        *reinterpret_cast<short8v*>(&Bs[srow][scol])     = b0r;
        *reinterpret_cast<short8v*>(&Bs[srow][scol + 8]) = b1r;
        __syncthreads();
        if (tt + 1 < nk) {
            const unsigned short* Ap2 = Ap + (tt + 1) * 64;
            const unsigned short* Bp2 = Bp + (tt + 1) * 64;
            a0r = *reinterpret_cast<const short8v*>(Ap2);
            a1r = *reinterpret_cast<const short8v*>(Ap2 + 8);
            b0r = *reinterpret_cast<const short8v*>(Bp2);
            b1r = *reinterpret_cast<const short8v*>(Bp2 + 8);
        }
#pragma unroll
        for (int kk = 0; kk < 2; ++kk) {
            short8v fa0 = *reinterpret_cast<const short8v*>(&As[wm + fr][kk * 32 + fq * 8]);
            short8v fa1 = *reinterpret_cast<const short8v*>(&As[wm + 16 + fr][kk * 32 + fq * 8]);
            short8v fb0 = *reinterpret_cast<const short8v*>(&Bs[wn + fr][kk * 32 + fq * 8]);
            short8v fb1 = *reinterpret_cast<const short8v*>(&Bs[wn + 16 + fr][kk * 32 + fq * 8]);
            acc[0][0] = __builtin_amdgcn_mfma_f32_16x16x32_bf16(fa0, fb0, acc[0][0], 0, 0, 0);
            acc[0][1] = __builtin_amdgcn_mfma_f32_16x16x32_bf16(fa0, fb1, acc[0][1], 0, 0, 0);
            acc[1][0] = __builtin_amdgcn_mfma_f32_16x16x32_bf16(fa1, fb0, acc[1][0], 0, 0, 0);
            acc[1][1] = __builtin_amdgcn_mfma_f32_16x16x32_bf16(fa1, fb1, acc[1][1], 0, 0, 0);
        }
        __syncthreads();
    }
    int dc = l & 15;
#pragma unroll
    for (int i = 0; i < 2; ++i)
#pragma unroll
        for (int j = 0; j < 2; ++j) {
            int c = col0 + wn + j * 16 + dc;
            if (c < N) {
                float bb = bias ? bias[c] : 0.f;
#pragma unroll
                for (int q = 0; q < 4; ++q) {
                    int r = row0 + wm + i * 16 + fq * 4 + q;
                    float v = acc[i][j][q] + bb;
                    long idx = (long)r * N + c;
                    if (C)  C[idx]  = v;
                    if (Cb) Cb[idx] = (unsigned short)f2bf(v);
                }
            }
        }
}

// ---------------- readout MFMA v2: prefetched, transposed-B ---------------------------------
__global__ __launch_bounds__(256) void readout_mfma2(const float* __restrict__ gn,
                                                     const unsigned short* __restrict__ HT,
                                                     float* __restrict__ vsum_part,
                                                     float* __restrict__ rowsum_part) {
    __shared__ unsigned short As[64][72];
    __shared__ unsigned short Bs[128][72];
    __shared__ float rsacc[64][4];
    int t = threadIdx.x, w = t >> 6, l = t & 63;
    int row0 = blockIdx.x * 64;
    int kc = blockIdx.y, kbeg = kc * 2048;
    int asr = t >> 2, asc = (t & 3) * 16;              // A: 16 f32 / thread
    int bsr = t >> 1, bsc = (t & 1) * 32;              // B: 32 bf16 / thread
    const float*          Ap = gn + (long)(row0 + asr) * NN + kbeg + asc;
    const unsigned short* Bp = HT + (long)bsr * NN + kbeg + bsc;
    int wm = (w >> 1) * 32, wn = (w & 1) * 64;
    int fr = l & 15, fq = l >> 4;

    float4  a4[4];
    short8v b8[4];
#pragma unroll
    for (int q = 0; q < 4; ++q) a4[q] = *reinterpret_cast<const float4*>(Ap + q * 4);
#pragma unroll
    for (int q = 0; q < 4; ++q) b8[q] = *reinterpret_cast<const short8v*>(Bp + q * 8);

    f32x4 acc[2][4] = {};
    float myrs = 0.f;
    for (int it = 0; it < 32; ++it) {
#pragma unroll
        for (int q = 0; q < 4; ++q) {
            float4 v = a4[q];
            ushort4 s;
            s.x = (unsigned short)f2bf(v.x);
            s.y = (unsigned short)f2bf(v.y);
            s.z = (unsigned short)f2bf(v.z);
            s.w = (unsigned short)f2bf(v.w);
            *reinterpret_cast<ushort4*>(&As[asr][asc + q * 4]) = s;
            myrs += v.x + v.y + v.z + v.w;
        }
#pragma unroll
        for (int q = 0; q < 4; ++q)
            *reinterpret_cast<short8v*>(&Bs[bsr][bsc + q * 8]) = b8[q];
        __syncthreads();
        if (it + 1 < 32) {
            const float*          Ap2 = Ap + (it + 1) * 64;
            const unsigned short* Bp2 = Bp + (it + 1) * 64;
#pragma unroll
            for (int q = 0; q < 4; ++q) a4[q] = *reinterpret_cast<const float4*>(Ap2 + q * 4);
#pragma unroll
            for (int q = 0; q < 4; ++q) b8[q] = *reinterpret_cast<const short8v*>(Bp2 + q * 8);
        }
#pragma unroll
        for (int kk = 0; kk < 2; ++kk) {
            short8v fa0 = *reinterpret_cast<const short8v*>(&As[wm + fr][kk * 32 + fq * 8]);
            short8v fa1 = *reinterpret_cast<const short8v*>(&As[wm + 16 + fr][kk * 32 + fq * 8]);
#pragma unroll
            for (int j = 0; j < 4; ++j) {
                short8v fb = *reinterpret_cast<const short8v*>(&Bs[wn + j * 16 + fr][kk * 32 + fq * 8]);
                acc[0][j] = __builtin_amdgcn_mfma_f32_16x16x32_bf16(fa0, fb, acc[0][j], 0, 0, 0);
                acc[1][j] = __builtin_amdgcn_mfma_f32_16x16x32_bf16(fa1, fb, acc[1][j], 0, 0, 0);
            }
        }
        __syncthreads();
    }
    rsacc[asr][t & 3] = myrs;
    __syncthreads();
    if (t < 64)
        rowsum_part[(long)kc * NN + row0 + t] =
            rsacc[t][0] + rsacc[t][1] + rsacc[t][2] + rsacc[t][3];
    int dc = l & 15;
#pragma unroll
    for (int i = 0; i < 2; ++i)
#pragma unroll
        for (int j = 0; j < 4; ++j) {
            int c = wn + j * 16 + dc;
#pragma unroll
            for (int q = 0; q < 4; ++q) {
                int r = row0 + wm + i * 16 + fq * 4 + q;
                vsum_part[((long)kc * NN + r) * 128 + c] = acc[i][j][q];
            }
        }
}

// ---------------- CSR build ----------------------------------------------------------------
__global__ void deg_count(const int* __restrict__ dst, int* __restrict__ deg) {
    int i = blockIdx.x * 256 + threadIdx.x;
    if (i < EE) atomicAdd(&deg[dst[i]], 1);
}

__global__ __launch_bounds__(256) void scan_offsets(const int* __restrict__ deg,
                                                    int* __restrict__ off,
                                                    int* __restrict__ cursor) {
    __shared__ int part[256];
    int t = threadIdx.x;
    int base = t * 32;
    int local[32];
    int s = 0;
#pragma unroll
    for (int i = 0; i < 32; ++i) { local[i] = s; s += deg[base + i]; }
    part[t] = s;
    __syncthreads();
    for (int o2 = 1; o2 < 256; o2 <<= 1) {
        int v = (t >= o2) ? part[t - o2] : 0;
        __syncthreads();
        part[t] += v;
        __syncthreads();
    }
    int pre = (t == 0) ? 0 : part[t - 1];
#pragma unroll
    for (int i = 0; i < 32; ++i) {
        int v = pre + local[i];
        off[base + i] = v;
        cursor[base + i] = v;
    }
}

__global__ void scatter_edges(const int* __restrict__ src, const int* __restrict__ dst,
                              int* __restrict__ cursor, int* __restrict__ ssrc) {
    int i = blockIdx.x * 256 + threadIdx.x;
    if (i >= EE) return;
    int slot = atomicAdd(&cursor[dst[i]], 1);
    ssrc[slot] = src[i];
}

// ---------------- attention coefficients (bf16 h) ------------------------------------------
__global__ void attn_coeff_bf(const unsigned short* __restrict__ h,
                              const float* __restrict__ att_src,
                              const float* __restrict__ att_dst,
                              float* __restrict__ a_src, float* __restrict__ a_dst) {
    int wave = threadIdx.x >> 6, lane = threadIdx.x & 63;
    int n = blockIdx.x * 4 + wave;
    ushort4 hv = *reinterpret_cast<const ushort4*>(&h[(long)n * HID + lane * 4]);
    float4 vs = *reinterpret_cast<const float4*>(&att_src[lane * 4]);
    float4 vd = *reinterpret_cast<const float4*>(&att_dst[lane * 4]);
    float h0 = bf2f(hv.x), h1 = bf2f(hv.y), h2v = bf2f(hv.z), h3v = bf2f(hv.w);
    float s1 = h0 * vs.x + h1 * vs.y + h2v * vs.z + h3v * vs.w;
    float s2 = h0 * vd.x + h1 * vd.y + h2v * vd.z + h3v * vd.w;
#pragma unroll
    for (int off = 32; off > 0; off >>= 1) {
        s1 += __shfl_down(s1, off);
        s2 += __shfl_down(s2, off);
    }
    if (lane == 0) { a_src[n] = s1; a_dst[n] = s2; }
}

// ---------------- fused GAT gather (bf16 h in, bf16 gat out) -------------------------------
__global__ __launch_bounds__(256) void gat_gather(const int* __restrict__ ssrc,
                                                  const int* __restrict__ off,
                                                  const int* __restrict__ deg,
                                                  const float* __restrict__ asrc,
                                                  const float* __restrict__ adst,
                                                  const unsigned short* __restrict__ h,
                                                  unsigned short* __restrict__ gat) {
    int wv = threadIdx.x >> 6, lane = threadIdx.x & 63;
    int d = blockIdx.x * 4 + wv;
    int o = off[d], n = deg[d];
    float ad = adst[d];

    float m = -INFINITY;
    for (int j = lane; j < n; j += 64) {
        float e = asrc[ssrc[o + j]] + ad;
        e = e > 0.f ? e : 0.2f * e;
        m = fmaxf(m, e);
    }
#pragma unroll
    for (int t = 32; t; t >>= 1) m = fmaxf(m, __shfl_xor(m, t));
    float z = 0.f;
    for (int j = lane; j < n; j += 64) {
        float e = asrc[ssrc[o + j]] + ad;
        e = e > 0.f ? e : 0.2f * e;
        z += expf(e - m);
    }
#pragma unroll
    for (int t = 32; t; t >>= 1) z += __shfl_xor(z, t);
    float zinv = 1.0f / (z + 1e-16f);

    float4 acc = {0.f, 0.f, 0.f, 0.f};
    int j = 0;
    for (; j + 2 <= n; j += 2) {
        int s0 = ssrc[o + j], s1 = ssrc[o + j + 1];
        const ushort4 h0 = *reinterpret_cast<const ushort4*>(&h[(long)s0 * HID + lane * 4]);
        const ushort4 h1 = *reinterpret_cast<const ushort4*>(&h[(long)s1 * HID + lane * 4]);
        float e0 = asrc[s0] + ad; e0 = e0 > 0.f ? e0 : 0.2f * e0;
        float e1 = asrc[s1] + ad; e1 = e1 > 0.f ? e1 : 0.2f * e1;
        float a0 = expf(e0 - m) * zinv;
        float a1 = expf(e1 - m) * zinv;
        acc.x += a0 * bf2f(h0.x) + a1 * bf2f(h1.x);
        acc.y += a0 * bf2f(h0.y) + a1 * bf2f(h1.y);
        acc.z += a0 * bf2f(h0.z) + a1 * bf2f(h1.z);
        acc.w += a0 * bf2f(h0.w) + a1 * bf2f(h1.w);
    }
    if (j < n) {
        int s0 = ssrc[o + j];
        const ushort4 h0 = *reinterpret_cast<const ushort4*>(&h[(long)s0 * HID + lane * 4]);
        float e0 = asrc[s0] + ad; e0 = e0 > 0.f ? e0 : 0.2f * e0;
        float a0 = expf(e0 - m) * zinv;
        acc.x += a0 * bf2f(h0.x); acc.y += a0 * bf2f(h0.y);
        acc.z += a0 * bf2f(h0.z); acc.w += a0 * bf2f(h0.w);
    }
    ushort4 r;
    r.x = (unsigned short)f2bf(acc.x > 0.f ? acc.x : expm1f(acc.x));
    r.y = (unsigned short)f2bf(acc.y > 0.f ? acc.y : expm1f(acc.y));
    r.z = (unsigned short)f2bf(acc.z > 0.f ? acc.z : expm1f(acc.z));
    r.w = (unsigned short)f2bf(acc.w > 0.f ? acc.w : expm1f(acc.w));
    *reinterpret_cast<ushort4*>(&gat[(long)d * HID + lane * 4]) = r;
}

// ---------------- batchnorm ----------------------------------------------------------------
__global__ void bn_partial(const float* __restrict__ zd, float* __restrict__ s,
                           float* __restrict__ sq) {
    int t = threadIdx.x;
    float a = 0.f, b = 0.f;
    int r0 = blockIdx.x * 128;
    for (int r = r0; r < r0 + 128; ++r) {
        float v = zd[(long)r * HID + t];
        a += v;
        b += v * v;
    }
    atomicAdd(&s[t], a);
    atomicAdd(&sq[t], b);
}

__global__ void bn_finalize(const float* __restrict__ s, const float* __restrict__ sq,
                            const float* __restrict__ gamma, const float* __restrict__ beta,
                            float* __restrict__ scale, float* __restrict__ shift) {
    int t = threadIdx.x;
    float mean = s[t] / (float)NN;
    float var  = sq[t] / (float)NN - mean * mean;
    float sc   = gamma[t] * rsqrtf(var + 1e-5f);
    scale[t] = sc;
    shift[t] = beta[t] - mean * sc;
}

__global__ void bn_apply_elu_bf(const float* __restrict__ zd, const float* __restrict__ scale,
                                const float* __restrict__ shift, unsigned short* __restrict__ zb) {
    for (long i = (long)blockIdx.x * blockDim.x + threadIdx.x; i < (long)NN * HID;
         i += (long)gridDim.x * blockDim.x) {
        int c = (int)(i & 255);
        float v = zd[i] * scale[c] + shift[c];
        v = v > 0.f ? v : expm1f(v);
        zb[i] = (unsigned short)f2bf(v);
    }
}

// ---------------- readout tail -------------------------------------------------------------
__global__ void pack_hcatT(const float* __restrict__ h2, const float* __restrict__ h2a,
                           unsigned short* __restrict__ HT) {
    int c = blockIdx.x;                  // 0..127
    int r = blockIdx.y * 256 + threadIdx.x;
    float v = (c < 64) ? h2[(long)r * 64 + c] : h2a[(long)r * 64 + (c - 64)];
    HT[(long)c * NN + r] = (unsigned short)f2bf(v);
}

__global__ void readout_norm2(const float* __restrict__ vsum_part,
                              const float* __restrict__ rowsum_part,
                              float* __restrict__ g, float* __restrict__ ga) {
    int r = blockIdx.x;
    int c = threadIdx.x;
    float v = 0.f;
#pragma unroll
    for (int kc = 0; kc < 4; ++kc)
        v += vsum_part[((long)kc * NN + r) * 128 + c];
    float rs = 0.f;
#pragma unroll
    for (int kc = 0; kc < 4; ++kc)
        rs += rowsum_part[(long)kc * NN + r];
    v /= rs;
    int w = c >> 6, lane = c & 63;
    float sq = v * v;
#pragma unroll
    for (int off = 32; off > 0; off >>= 1) sq += __shfl_xor(sq, off);
    float nrm = fmaxf(sqrtf(sq), 1e-12f);
    float out = 1.0f / (1.0f + expf(-(v / nrm)));
    (w == 0 ? g : ga)[(long)r * 64 + lane] = out;
}

// ---------------- discriminator ------------------------------------------------------------
__global__ void disc_kernel(const float* __restrict__ h2, const float* __restrict__ h2a,
                            const float* __restrict__ g, const float* __restrict__ ga,
                            const float* __restrict__ W, const float* __restrict__ b,
                            float* __restrict__ ret, float* __restrict__ reta) {
    int n = blockIdx.x;
    int w = threadIdx.x >> 6, lane = threadIdx.x & 63;
    const float* c = (w == 0) ? g : ga;
    float u = 0.f;
#pragma unroll 8
    for (int e = 0; e < 64; ++e) u += W[lane * 64 + e] * c[(long)n * 64 + e];
    float hp = ((w == 0) ? h2 : h2a)[(long)n * 64 + lane];
    float hm = ((w == 0) ? h2a : h2)[(long)n * 64 + lane];
    float t1 = hp * u, t2 = hm * u;
    for (int off = 32; off > 0; off >>= 1) {
        t1 += __shfl_xor(t1, off);
        t2 += __shfl_xor(t2, off);
    }
    if (lane == 0) {
        float bb = b[0];
        if (w == 0) { ret[n * 2] = t1 + bb;  ret[n * 2 + 1] = t2 + bb; }
        else        { reta[n * 2] = t1 + bb; reta[n * 2 + 1] = t2 + bb; }
    }
}

__global__ void copy_h2(const float* __restrict__ h2, const float* __restrict__ h2a,
                        float* __restrict__ out) {
    int i = blockIdx.x * 256 + threadIdx.x;
    float v = h2[i], va = h2a[i];
    out[O_H2 + i]  = v;
    out[O_H2B + i] = v;
    out[O_H2A + i] = va;
}

// ---------------- driver -------------------------------------------------------------------
extern "C" void kernel_launch(void* const* d_in, const int* in_sizes, int n_in,
                              void* d_out, int out_size, void* d_ws, size_t ws_size,
                              hipStream_t stream) {
    const float* feat    = (const float*)d_in[0];
    const float* feat_a  = (const float*)d_in[1];
    const float* gneigh  = (const float*)d_in[2];
    const float* W1      = (const float*)d_in[3];
    const float* att_src = (const float*)d_in[4];
    const float* att_dst = (const float*)d_in[5];
    const float* W2      = (const float*)d_in[6];
    const float* Wd1     = (const float*)d_in[7];
    const float* bd1     = (const float*)d_in[8];
    const float* gamma   = (const float*)d_in[9];
    const float* beta    = (const float*)d_in[10];
    const float* Wd2     = (const float*)d_in[11];
    const float* bd2     = (const float*)d_in[12];
    const float* disc_W  = (const float*)d_in[13];
    const float* disc_b  = (const float*)d_in[14];
    const int*   eidx    = (const int*)d_in[15];
    const int*   src = eidx;
    const int*   dst = eidx + EE;
    float* out = (float*)d_out;

    // workspace layout (floats)
    float* w = (float*)d_ws;
    float* h_buf   = w;                                            // 2097152 f (8 MB)
    unsigned short* h_bf = (unsigned short*)h_buf;                 // 8192*256 bf16 (4 MB)
    unsigned short* gat_bf = (unsigned short*)(h_buf + 2097152);   // 4 MB
    float* zdec    = h_buf + 2097152 + 1048576;                    // 2097152 f (8 MB)
    unsigned short* zdec_bf = (unsigned short*)(zdec + 2097152);   // 4 MB
    float* h2      = zdec + 2097152 + 1048576;                     // 524288
    float* h2a     = h2 + 524288;             // 524288
    float* gbuf    = h2a + 524288;            // 524288
    float* gabuf   = gbuf + 524288;           // 524288
    unsigned short* h2b = (unsigned short*)(gabuf + 524288);       // 262144 f
    float* asrc    = gabuf + 524288 + 262144; // 8192
    float* adst    = asrc + 8192;             // 8192
    float* bnsum   = adst + 8192;             // 256
    float* bnsq    = bnsum + 256;             // 256
    float* scale   = bnsq + 256;              // 256
    float* shift   = scale + 256;             // 256
    unsigned short* W1t  = (unsigned short*)(shift + 256);         // 770048 sh
    unsigned short* W2t  = W1t + 770048;                           // 16384 sh
    unsigned short* Wd1t = W2t + 16384;                            // 16384 sh
    unsigned short* Wd2t = Wd1t + 16384;                           // 786432 sh (3072 rows)
    int*   ideg    = (int*)(Wd2t + 786432);   // 8192
    int*   ioff    = ideg + 8192;             // 8192
    int*   icur    = ioff + 8192;             // 8192
    int*   issrc   = icur + 8192;             // 262144
    // split-K partials for the feat GEMM: 2 x [8192][256] f32 = 16 MB,
    // spans gat_bf + zdec + zdec_bf (all dead during the feat GEMM)
    float* part = w + 2097152;
    // readout-phase reuse (h_buf..zdec dead after decoder):
    float* vsum_part = h_buf;                 // 4*8192*128 f = 16 MB
    unsigned short* HT = zdec_bf;             // 128*8192 bf16 = 2 MB
    float* rowsum_part = ((float*)zdec_bf) + 524288;               // 4*8192 f

    // ---- one-time weight conversions (transposed + padded)
    cvt_W1t<<<3008, 256, 0, stream>>>(W1, W1t);
    cvt_W2t<<<64, 256, 0, stream>>>(W2, W2t);
    cvt_Wd1t<<<64, 256, 0, stream>>>(Wd1, Wd1t);
    cvt_Wd2t<<<3072, 256, 0, stream>>>(Wd2, Wd2t);

    // ---- CSR build (edge_index shared by both encode passes)
    hipMemsetAsync(ideg, 0, 8192 * 4, stream);
    deg_count<<<EE / 256, 256, 0, stream>>>(dst, ideg);
    scan_offsets<<<1, 256, 0, stream>>>(ideg, ioff, icur);
    scatter_edges<<<EE / 256, 256, 0, stream>>>(src, dst, icur, issrc);

    auto encode_pass = [&](const float* x, float* h2_out) {
        // h = x @ W1: 128x128 tile, f32 A with fused conversion, split-K=2 -> partials
        mfma_gemm128<1><<<dim3(2, 64, 2), 256, 0, stream>>>(
            x, W1t, nullptr, nullptr, part, NN, HID, IN, INP, IN, 24, 47);
        reduce_cvt<<<2048, 256, 0, stream>>>(part, h_bf);
        attn_coeff_bf<<<2048, 256, 0, stream>>>(h_bf, att_src, att_dst, asrc, adst);
        gat_gather<<<2048, 256, 0, stream>>>(issrc, ioff, ideg, asrc, adst, h_bf, gat_bf);
        // h2 = h1 @ W2 -> f32 h2 (+ bf16 h2b)
        mfma_gemm_bf<<<dim3(1, 128), 256, 0, stream>>>(gat_bf, W2t, nullptr,
                                                       h2_out, h2b, NN, OUT, HID);
    };

    encode_pass(feat, h2);
    encode_pass(feat_a, h2a);     // clobbers h2b with bf16(h2a)
    cvt_f2b<<<2048, 256, 0, stream>>>(h2, h2b);   // restore h2b = bf16(h2)

    // ---- decoder: h3 = elu(BN(h2 @ Wd1 + bd1)) @ Wd2 + bd2
    mfma_gemm_bf<<<dim3(4, 128), 256, 0, stream>>>(h2b, Wd1t, bd1,
                                                   zdec, nullptr, NN, HID, OUT);
    hipMemsetAsync(bnsum, 0, 512 * 4, stream);
    bn_partial<<<64, 256, 0, stream>>>(zdec, bnsum, bnsq);
    bn_finalize<<<1, 256, 0, stream>>>(bnsum, bnsq, gamma, beta, scale, shift);
    bn_apply_elu_bf<<<2048, 256, 0, stream>>>(zdec, scale, shift, zdec_bf);
    // h3 = zn @ Wd2 + bd2: 128x128 tile, bf16 A
    mfma_gemm128<0><<<dim3(24, 64, 1), 256, 0, stream>>>(
        zdec_bf, Wd2t, bd2, out + O_H3, nullptr, NN, IN, HID, HID, HID, 4, 4);

    // ---- readout (zdec_bf region free now -> HT)
    pack_hcatT<<<dim3(128, 32), 256, 0, stream>>>(h2, h2a, HT);
    readout_mfma2<<<dim3(128, 4), 256, 0, stream>>>(gneigh, HT, vsum_part, rowsum_part);
    readout_norm2<<<8192, 128, 0, stream>>>(vsum_part, rowsum_part, gbuf, gabuf);

    // ---- discriminator
    disc_kernel<<<8192, 128, 0, stream>>>(h2, h2a, gbuf, gabuf, disc_W, disc_b,
                                          out + O_RET, out + O_RETA);

    // ---- copy h2 outputs (slots 0, 4, 5)
    copy_h2<<<2048, 256, 0, stream>>>(h2, h2a, out);
}

// Round 11
// 419.466 us; speedup vs baseline: 1.0723x; 1.0723x over previous
//
#include <hip/hip_runtime.h>
#include <hip/hip_bf16.h>
#include <math.h>

// Problem dims
constexpr int NN  = 8192;
constexpr int EE  = 262144;
constexpr int IN  = 3000;
constexpr int INP = 3008;   // IN padded to mult of 64
constexpr int HID = 256;
constexpr int OUT = 64;

// Output offsets (floats) in d_out: (h2, h3, ret, ret_a, h2, h2_a)
constexpr long O_H2   = 0;
constexpr long O_H3   = 524288;          // 8192*64
constexpr long O_RET  = 25100288;        // + 8192*3000
constexpr long O_RETA = 25116672;        // + 8192*2
constexpr long O_H2B  = 25133056;        // + 8192*2
constexpr long O_H2A  = 25657344;        // + 8192*64

typedef __attribute__((ext_vector_type(8))) short short8v;   // 8 bf16 (4 VGPRs)
typedef __attribute__((ext_vector_type(4))) float f32x4;     // MFMA accumulator

__device__ __forceinline__ short f2bf(float f) {   // RNE f32 -> bf16 bits
    unsigned u = __float_as_uint(f);
    return (short)((u + 0x7FFF + ((u >> 16) & 1)) >> 16);
}
__device__ __forceinline__ float bf2f(unsigned short u) {
    return __uint_as_float(((unsigned)u) << 16);
}

// ================= conversion kernels (one-time per launch) ================================
__global__ void cvt_W1t(const float* __restrict__ W, unsigned short* __restrict__ Wt) {
    int i = blockIdx.x * 256 + threadIdx.x;            // over 256*3008
    int n = i / INP, k = i % INP;
    Wt[i] = (k < IN) ? (unsigned short)f2bf(W[(long)k * HID + n]) : 0;
}
__global__ void cvt_W2t(const float* __restrict__ W, unsigned short* __restrict__ Wt) {
    int i = blockIdx.x * 256 + threadIdx.x;            // over 64*256
    int n = i / HID, k = i % HID;
    Wt[i] = (unsigned short)f2bf(W[(long)k * OUT + n]);
}
__global__ void cvt_Wd1t(const float* __restrict__ W, unsigned short* __restrict__ Wt) {
    int i = blockIdx.x * 256 + threadIdx.x;            // over 256*64
    int n = i / OUT, k = i % OUT;
    Wt[i] = (unsigned short)f2bf(W[(long)k * HID + n]);
}
__global__ void cvt_Wd2t(const float* __restrict__ W, unsigned short* __restrict__ Wt) {
    int i = blockIdx.x * 256 + threadIdx.x;            // over 3072*256
    int n = i / HID, k = i % HID;
    Wt[i] = (n < IN) ? (unsigned short)f2bf(W[(long)k * IN + n]) : 0;
}

// ================= feat GEMM: [feat;feat_a][16384,3000] @ W1 -> h_bf2 bf16 =================
// 128x128 tile, BK=64, reg-prefetch, f32 A converted during staging, bf16 epilogue.
// grid = 256 blocks exactly; decode x=id>>7 so the two N-tiles of a row-panel share an XCD.
__global__ __launch_bounds__(256) void feat_gemm(const float* __restrict__ A0,
                                                 const float* __restrict__ A1,
                                                 const unsigned short* __restrict__ Bt,
                                                 unsigned short* __restrict__ Hb) {
    __shared__ unsigned short As[128][72];
    __shared__ unsigned short Bs[128][72];
    int id = blockIdx.x;
    int xb = id >> 7, yb = id & 127;        // yb 0..127 over both passes
    int pass = yb >> 6;
    int row0 = (yb & 63) * 128, col0 = xb * 128;
    const float* A = pass ? A1 : A0;
    int t = threadIdx.x, w = t >> 6, l = t & 63;
    int sr = t >> 1, sh = (t & 1) * 32;
    int wm = (w >> 1) * 64, wn = (w & 1) * 64;
    int fr = l & 15, fq = l >> 4;
    const unsigned short* Bp = Bt + (long)(col0 + sr) * INP + sh;
    const float* Arow = A + (long)(row0 + sr) * IN;

    float4  paf[8];
    short8v pb[4];
    auto loadA = [&](int k0) {
        const float* Ar = Arow + k0 + sh;
        if (k0 + 64 <= IN) {
#pragma unroll
            for (int q = 0; q < 8; ++q) paf[q] = *reinterpret_cast<const float4*>(Ar + q * 4);
        } else {
#pragma unroll
            for (int q = 0; q < 8; ++q) {
                int kb = k0 + sh + q * 4;
                float4 v;
                v.x = (kb + 0 < IN) ? Ar[q * 4 + 0] : 0.f;
                v.y = (kb + 1 < IN) ? Ar[q * 4 + 1] : 0.f;
                v.z = (kb + 2 < IN) ? Ar[q * 4 + 2] : 0.f;
                v.w = (kb + 3 < IN) ? Ar[q * 4 + 3] : 0.f;
                paf[q] = v;
            }
        }
    };
    auto loadB = [&](int k0) {
#pragma unroll
        for (int q = 0; q < 4; ++q) pb[q] = *reinterpret_cast<const short8v*>(Bp + k0 + q * 8);
    };
    loadA(0); loadB(0);

    constexpr int NK = INP / 64;   // 47
    f32x4 acc[4][4] = {};
    for (int tt = 0; tt < NK; ++tt) {
#pragma unroll
        for (int q = 0; q < 4; ++q) {
            float4 v0 = paf[q * 2], v1 = paf[q * 2 + 1];
            short8v s;
            s[0]=f2bf(v0.x); s[1]=f2bf(v0.y); s[2]=f2bf(v0.z); s[3]=f2bf(v0.w);
            s[4]=f2bf(v1.x); s[5]=f2bf(v1.y); s[6]=f2bf(v1.z); s[7]=f2bf(v1.w);
            *reinterpret_cast<short8v*>(&As[sr][sh + q * 8]) = s;
        }
#pragma unroll
        for (int q = 0; q < 4; ++q)
            *reinterpret_cast<short8v*>(&Bs[sr][sh + q * 8]) = pb[q];
        __syncthreads();
        if (tt + 1 < NK) { loadA((tt + 1) * 64); loadB((tt + 1) * 64); }
#pragma unroll
        for (int kk = 0; kk < 2; ++kk) {
            short8v fa[4], fb[4];
#pragma unroll
            for (int i = 0; i < 4; ++i)
                fa[i] = *reinterpret_cast<const short8v*>(&As[wm + i * 16 + fr][kk * 32 + fq * 8]);
#pragma unroll
            for (int j = 0; j < 4; ++j)
                fb[j] = *reinterpret_cast<const short8v*>(&Bs[wn + j * 16 + fr][kk * 32 + fq * 8]);
#pragma unroll
            for (int i = 0; i < 4; ++i)
#pragma unroll
                for (int j = 0; j < 4; ++j)
                    acc[i][j] = __builtin_amdgcn_mfma_f32_16x16x32_bf16(fa[i], fb[j], acc[i][j], 0, 0, 0);
        }
        __syncthreads();
    }
    int dc = l & 15;
    long base = (long)(pass * NN) * HID;
#pragma unroll
    for (int i = 0; i < 4; ++i)
#pragma unroll
        for (int j = 0; j < 4; ++j) {
            int c = col0 + wn + j * 16 + dc;
#pragma unroll
            for (int q = 0; q < 4; ++q) {
                int r = row0 + wm + i * 16 + fq * 4 + q;
                Hb[base + (long)r * HID + c] = (unsigned short)f2bf(acc[i][j][q]);
            }
        }
}

// ================= W2 GEMM with mega-epilogue ==============================================
// gat_bf2[16384][256] @ W2t[64][256]^T. Writes h2f (f32, disc), d_out h2 slots, h2b (bf16,
// pass0 only), HT (bf16 transposed). 64x64 tile, grid dim3(1,256).
__global__ __launch_bounds__(256) void w2_gemm(const unsigned short* __restrict__ A,
                                               const unsigned short* __restrict__ Bt,
                                               float* __restrict__ h2f,
                                               unsigned short* __restrict__ h2b,
                                               unsigned short* __restrict__ HT,
                                               float* __restrict__ out) {
    __shared__ unsigned short As[64][72];
    __shared__ unsigned short Bs[64][72];
    int t = threadIdx.x, w = t >> 6, l = t & 63;
    int row0 = blockIdx.y * 64;
    int srow = t >> 2, scol = (t & 3) * 16;
    const unsigned short* Ap = A + (long)(row0 + srow) * HID + scol;
    const unsigned short* Bp = Bt + (long)srow * HID + scol;   // 64 rows only
    int wm = (w >> 1) * 32, wn = (w & 1) * 32;
    int fr = l & 15, fq = l >> 4;

    short8v a0r, a1r, b0r, b1r;
    a0r = *reinterpret_cast<const short8v*>(Ap);
    a1r = *reinterpret_cast<const short8v*>(Ap + 8);
    b0r = *reinterpret_cast<const short8v*>(Bp);
    b1r = *reinterpret_cast<const short8v*>(Bp + 8);

    f32x4 acc[2][2] = {};
    for (int tt = 0; tt < 4; ++tt) {
        *reinterpret_cast<short8v*>(&As[srow][scol])     = a0r;
        *reinterpret_cast<short8v*>(&As[srow][scol + 8]) = a1r;
        *reinterpret_cast<short8v*>(&Bs[srow][scol])     = b0r;
        *reinterpret_cast<short8v*>(&Bs[srow][scol + 8]) = b1r;
        __syncthreads();
        if (tt + 1 < 4) {
            const unsigned short* Ap2 = Ap + (tt + 1) * 64;
            const unsigned short* Bp2 = Bp + (tt + 1) * 64;
            a0r = *reinterpret_cast<const short8v*>(Ap2);
            a1r = *reinterpret_cast<const short8v*>(Ap2 + 8);
            b0r = *reinterpret_cast<const short8v*>(Bp2);
            b1r = *reinterpret_cast<const short8v*>(Bp2 + 8);
        }
#pragma unroll
        for (int kk = 0; kk < 2; ++kk) {
            short8v fa0 = *reinterpret_cast<const short8v*>(&As[wm + fr][kk * 32 + fq * 8]);
            short8v fa1 = *reinterpret_cast<const short8v*>(&As[wm + 16 + fr][kk * 32 + fq * 8]);
            short8v fb0 = *reinterpret_cast<const short8v*>(&Bs[wn + fr][kk * 32 + fq * 8]);
            short8v fb1 = *reinterpret_cast<const short8v*>(&Bs[wn + 16 + fr][kk * 32 + fq * 8]);
            acc[0][0] = __builtin_amdgcn_mfma_f32_16x16x32_bf16(fa0, fb0, acc[0][0], 0, 0, 0);
            acc[0][1] = __builtin_amdgcn_mfma_f32_16x16x32_bf16(fa0, fb1, acc[0][1], 0, 0, 0);
            acc[1][0] = __builtin_amdgcn_mfma_f32_16x16x32_bf16(fa1, fb0, acc[1][0], 0, 0, 0);
            acc[1][1] = __builtin_amdgcn_mfma_f32_16x16x32_bf16(fa1, fb1, acc[1][1], 0, 0, 0);
        }
        __syncthreads();
    }
    int dc = l & 15;
    int pass = row0 >> 13;
#pragma unroll
    for (int i = 0; i < 2; ++i)
#pragma unroll
        for (int j = 0; j < 2; ++j) {
            int c = wn + j * 16 + dc;
#pragma unroll
            for (int q = 0; q < 4; ++q) {
                int r = row0 + wm + i * 16 + fq * 4 + q;
                int n = r & 8191;
                float v = acc[i][j][q];
                unsigned short vb = (unsigned short)f2bf(v);
                h2f[(long)pass * 524288 + (long)n * 64 + c] = v;
                if (pass == 0) {
                    out[O_H2  + (long)n * 64 + c] = v;
                    out[O_H2B + (long)n * 64 + c] = v;
                    h2b[(long)n * 64 + c] = vb;
                } else {
                    out[O_H2A + (long)n * 64 + c] = v;
                }
                HT[(long)(pass * 64 + c) * NN + n] = vb;
            }
        }
}

// ================= 128x128 bf16 GEMM (Wd2) ================================================
__global__ __launch_bounds__(256) void wd2_gemm(const unsigned short* __restrict__ A,
                                                const unsigned short* __restrict__ Bt,
                                                const float* __restrict__ bias,
                                                float* __restrict__ Cf) {
    __shared__ unsigned short As[128][72];
    __shared__ unsigned short Bs[128][72];
    int t = threadIdx.x, w = t >> 6, l = t & 63;
    int row0 = blockIdx.y * 128, col0 = blockIdx.x * 128;
    int sr = t >> 1, sh = (t & 1) * 32;
    int wm = (w >> 1) * 64, wn = (w & 1) * 64;
    int fr = l & 15, fq = l >> 4;
    const unsigned short* Ap = A  + (long)(row0 + sr) * HID + sh;
    const unsigned short* Bp = Bt + (long)(col0 + sr) * HID + sh;

    short8v pa[4], pb[4];
#pragma unroll
    for (int q = 0; q < 4; ++q) pa[q] = *reinterpret_cast<const short8v*>(Ap + q * 8);
#pragma unroll
    for (int q = 0; q < 4; ++q) pb[q] = *reinterpret_cast<const short8v*>(Bp + q * 8);

    f32x4 acc[4][4] = {};
    for (int tt = 0; tt < 4; ++tt) {
#pragma unroll
        for (int q = 0; q < 4; ++q) {
            *reinterpret_cast<short8v*>(&As[sr][sh + q * 8]) = pa[q];
            *reinterpret_cast<short8v*>(&Bs[sr][sh + q * 8]) = pb[q];
        }
        __syncthreads();
        if (tt + 1 < 4) {
            int k0 = (tt + 1) * 64;
#pragma unroll
            for (int q = 0; q < 4; ++q) pa[q] = *reinterpret_cast<const short8v*>(Ap + k0 + q * 8);
#pragma unroll
            for (int q = 0; q < 4; ++q) pb[q] = *reinterpret_cast<const short8v*>(Bp + k0 + q * 8);
        }
#pragma unroll
        for (int kk = 0; kk < 2; ++kk) {
            short8v fa[4], fb[4];
#pragma unroll
            for (int i = 0; i < 4; ++i)
                fa[i] = *reinterpret_cast<const short8v*>(&As[wm + i * 16 + fr][kk * 32 + fq * 8]);
#pragma unroll
            for (int j = 0; j < 4; ++j)
                fb[j] = *reinterpret_cast<const short8v*>(&Bs[wn + j * 16 + fr][kk * 32 + fq * 8]);
#pragma unroll
            for (int i = 0; i < 4; ++i)
#pragma unroll
                for (int j = 0; j < 4; ++j)
                    acc[i][j] = __builtin_amdgcn_mfma_f32_16x16x32_bf16(fa[i], fb[j], acc[i][j], 0, 0, 0);
        }
        __syncthreads();
    }
    int dc = l & 15;
#pragma unroll
    for (int i = 0; i < 4; ++i)
#pragma unroll
        for (int j = 0; j < 4; ++j) {
            int c = col0 + wn + j * 16 + dc;
            if (c < IN) {
                float bb = bias[c];
#pragma unroll
                for (int q = 0; q < 4; ++q) {
                    int r = row0 + wm + i * 16 + fq * 4 + q;
                    Cf[(long)r * IN + c] = acc[i][j][q] + bb;
                }
            }
        }
}

// ================= 64x64 bf16 GEMM (Wd1) ===================================================
__global__ __launch_bounds__(256) void wd1_gemm(const unsigned short* __restrict__ A,
                                                const unsigned short* __restrict__ Bt,
                                                const float* __restrict__ bias,
                                                float* __restrict__ C) {
    __shared__ unsigned short As[64][72];
    __shared__ unsigned short Bs[64][72];
    int t = threadIdx.x, w = t >> 6, l = t & 63;
    int row0 = blockIdx.y * 64, col0 = blockIdx.x * 64;
    int srow = t >> 2, scol = (t & 3) * 16;
    const unsigned short* Ap = A  + (long)(row0 + srow) * OUT + scol;   // K=64
    const unsigned short* Bp = Bt + (long)(col0 + srow) * OUT + scol;
    int wm = (w >> 1) * 32, wn = (w & 1) * 32;
    int fr = l & 15, fq = l >> 4;

    // K=64: single tile, no loop
    *reinterpret_cast<short8v*>(&As[srow][scol])     = *reinterpret_cast<const short8v*>(Ap);
    *reinterpret_cast<short8v*>(&As[srow][scol + 8]) = *reinterpret_cast<const short8v*>(Ap + 8);
    *reinterpret_cast<short8v*>(&Bs[srow][scol])     = *reinterpret_cast<const short8v*>(Bp);
    *reinterpret_cast<short8v*>(&Bs[srow][scol + 8]) = *reinterpret_cast<const short8v*>(Bp + 8);
    __syncthreads();
    f32x4 acc[2][2] = {};
#pragma unroll
    for (int kk = 0; kk < 2; ++kk) {
        short8v fa0 = *reinterpret_cast<const short8v*>(&As[wm + fr][kk * 32 + fq * 8]);
        short8v fa1 = *reinterpret_cast<const short8v*>(&As[wm + 16 + fr][kk * 32 + fq * 8]);
        short8v fb0 = *reinterpret_cast<const short8v*>(&Bs[wn + fr][kk * 32 + fq * 8]);
        short8v fb1 = *reinterpret_cast<const short8v*>(&Bs[wn + 16 + fr][kk * 32 + fq * 8]);
        acc[0][0] = __builtin_amdgcn_mfma_f32_16x16x32_bf16(fa0, fb0, acc[0][0], 0, 0, 0);
        acc[0][1] = __builtin_amdgcn_mfma_f32_16x16x32_bf16(fa0, fb1, acc[0][1], 0, 0, 0);
        acc[1][0] = __builtin_amdgcn_mfma_f32_16x16x32_bf16(fa1, fb0, acc[1][0], 0, 0, 0);
        acc[1][1] = __builtin_amdgcn_mfma_f32_16x16x32_bf16(fa1, fb1, acc[1][1], 0, 0, 0);
    }
    int dc = l & 15;
#pragma unroll
    for (int i = 0; i < 2; ++i)
#pragma unroll
        for (int j = 0; j < 2; ++j) {
            int c = col0 + wn + j * 16 + dc;
            float bb = bias[c];
#pragma unroll
            for (int q = 0; q < 4; ++q) {
                int r = row0 + wm + i * 16 + fq * 4 + q;
                C[(long)r * HID + c] = acc[i][j][q] + bb;
            }
        }
}

// ---------------- readout MFMA: prefetched, transposed-B -----------------------------------
__global__ __launch_bounds__(256) void readout_mfma2(const float* __restrict__ gn,
                                                     const unsigned short* __restrict__ HT,
                                                     float* __restrict__ vsum_part,
                                                     float* __restrict__ rowsum_part) {
    __shared__ unsigned short As[64][72];
    __shared__ unsigned short Bs[128][72];
    __shared__ float rsacc[64][4];
    int t = threadIdx.x, w = t >> 6, l = t & 63;
    int row0 = blockIdx.x * 64;
    int kc = blockIdx.y, kbeg = kc * 2048;
    int asr = t >> 2, asc = (t & 3) * 16;
    int bsr = t >> 1, bsc = (t & 1) * 32;
    const float*          Ap = gn + (long)(row0 + asr) * NN + kbeg + asc;
    const unsigned short* Bp = HT + (long)bsr * NN + kbeg + bsc;
    int wm = (w >> 1) * 32, wn = (w & 1) * 64;
    int fr = l & 15, fq = l >> 4;

    float4  a4[4];
    short8v b8[4];
#pragma unroll
    for (int q = 0; q < 4; ++q) a4[q] = *reinterpret_cast<const float4*>(Ap + q * 4);
#pragma unroll
    for (int q = 0; q < 4; ++q) b8[q] = *reinterpret_cast<const short8v*>(Bp + q * 8);

    f32x4 acc[2][4] = {};
    float myrs = 0.f;
    for (int it = 0; it < 32; ++it) {
#pragma unroll
        for (int q = 0; q < 4; ++q) {
            float4 v = a4[q];
            ushort4 s;
            s.x = (unsigned short)f2bf(v.x);
            s.y = (unsigned short)f2bf(v.y);
            s.z = (unsigned short)f2bf(v.z);
            s.w = (unsigned short)f2bf(v.w);
            *reinterpret_cast<ushort4*>(&As[asr][asc + q * 4]) = s;
            myrs += v.x + v.y + v.z + v.w;
        }
#pragma unroll
        for (int q = 0; q < 4; ++q)
            *reinterpret_cast<short8v*>(&Bs[bsr][bsc + q * 8]) = b8[q];
        __syncthreads();
        if (it + 1 < 32) {
            const float*          Ap2 = Ap + (it + 1) * 64;
            const unsigned short* Bp2 = Bp + (it + 1) * 64;
#pragma unroll
            for (int q = 0; q < 4; ++q) a4[q] = *reinterpret_cast<const float4*>(Ap2 + q * 4);
#pragma unroll
            for (int q = 0; q < 4; ++q) b8[q] = *reinterpret_cast<const short8v*>(Bp2 + q * 8);
        }
#pragma unroll
        for (int kk = 0; kk < 2; ++kk) {
            short8v fa0 = *reinterpret_cast<const short8v*>(&As[wm + fr][kk * 32 + fq * 8]);
            short8v fa1 = *reinterpret_cast<const short8v*>(&As[wm + 16 + fr][kk * 32 + fq * 8]);
#pragma unroll
            for (int j = 0; j < 4; ++j) {
                short8v fb = *reinterpret_cast<const short8v*>(&Bs[wn + j * 16 + fr][kk * 32 + fq * 8]);
                acc[0][j] = __builtin_amdgcn_mfma_f32_16x16x32_bf16(fa0, fb, acc[0][j], 0, 0, 0);
                acc[1][j] = __builtin_amdgcn_mfma_f32_16x16x32_bf16(fa1, fb, acc[1][j], 0, 0, 0);
            }
        }
        __syncthreads();
    }
    rsacc[asr][t & 3] = myrs;
    __syncthreads();
    if (t < 64)
        rowsum_part[(long)kc * NN + row0 + t] =
            rsacc[t][0] + rsacc[t][1] + rsacc[t][2] + rsacc[t][3];
    int dc = l & 15;
#pragma unroll
    for (int i = 0; i < 2; ++i)
#pragma unroll
        for (int j = 0; j < 4; ++j) {
            int c = wn + j * 16 + dc;
#pragma unroll
            for (int q = 0; q < 4; ++q) {
                int r = row0 + wm + i * 16 + fq * 4 + q;
                vsum_part[((long)kc * NN + r) * 128 + c] = acc[i][j][q];
            }
        }
}

// ---------------- CSR build ----------------------------------------------------------------
__global__ void deg_count(const int* __restrict__ dst, int* __restrict__ deg) {
    int i = blockIdx.x * 256 + threadIdx.x;
    if (i < EE) atomicAdd(&deg[dst[i]], 1);
}

__global__ __launch_bounds__(256) void scan_offsets(const int* __restrict__ deg,
                                                    int* __restrict__ off,
                                                    int* __restrict__ cursor) {
    __shared__ int part[256];
    int t = threadIdx.x;
    int base = t * 32;
    int local[32];
    int s = 0;
#pragma unroll
    for (int i = 0; i < 32; ++i) { local[i] = s; s += deg[base + i]; }
    part[t] = s;
    __syncthreads();
    for (int o2 = 1; o2 < 256; o2 <<= 1) {
        int v = (t >= o2) ? part[t - o2] : 0;
        __syncthreads();
        part[t] += v;
        __syncthreads();
    }
    int pre = (t == 0) ? 0 : part[t - 1];
#pragma unroll
    for (int i = 0; i < 32; ++i) {
        int v = pre + local[i];
        off[base + i] = v;
        cursor[base + i] = v;
    }
}

__global__ void scatter_edges(const int* __restrict__ src, const int* __restrict__ dst,
                              int* __restrict__ cursor, int* __restrict__ ssrc) {
    int i = blockIdx.x * 256 + threadIdx.x;
    if (i >= EE) return;
    int slot = atomicAdd(&cursor[dst[i]], 1);
    ssrc[slot] = src[i];
}

// ---------------- attention coefficients (batched both passes) -----------------------------
__global__ void attn_coeff_bf(const unsigned short* __restrict__ h,
                              const float* __restrict__ att_src,
                              const float* __restrict__ att_dst,
                              float* __restrict__ a_src, float* __restrict__ a_dst) {
    int wave = threadIdx.x >> 6, lane = threadIdx.x & 63;
    int n = blockIdx.x * 4 + wave;      // 0..16383
    ushort4 hv = *reinterpret_cast<const ushort4*>(&h[(long)n * HID + lane * 4]);
    float4 vs = *reinterpret_cast<const float4*>(&att_src[lane * 4]);
    float4 vd = *reinterpret_cast<const float4*>(&att_dst[lane * 4]);
    float h0 = bf2f(hv.x), h1 = bf2f(hv.y), h2v = bf2f(hv.z), h3v = bf2f(hv.w);
    float s1 = h0 * vs.x + h1 * vs.y + h2v * vs.z + h3v * vs.w;
    float s2 = h0 * vd.x + h1 * vd.y + h2v * vd.z + h3v * vd.w;
#pragma unroll
    for (int off = 32; off > 0; off >>= 1) {
        s1 += __shfl_down(s1, off);
        s2 += __shfl_down(s2, off);
    }
    if (lane == 0) { a_src[n] = s1; a_dst[n] = s2; }
}

// ---------------- fused GAT gather (batched both passes) -----------------------------------
__global__ __launch_bounds__(256) void gat_gather(const int* __restrict__ ssrc,
                                                  const int* __restrict__ off,
                                                  const int* __restrict__ deg,
                                                  const float* __restrict__ asrc2,
                                                  const float* __restrict__ adst2,
                                                  const unsigned short* __restrict__ hb2,
                                                  unsigned short* __restrict__ gat2) {
    int wv = threadIdx.x >> 6, lane = threadIdx.x & 63;
    int d = blockIdx.x * 4 + wv;        // 0..16383
    int pass = d >> 13, node = d & 8191;
    const float* asrc = asrc2 + pass * NN;
    const unsigned short* h = hb2 + (long)pass * NN * HID;
    int o = off[node], n = deg[node];
    float ad = adst2[d];

    float m = -INFINITY;
    for (int j = lane; j < n; j += 64) {
        float e = asrc[ssrc[o + j]] + ad;
        e = e > 0.f ? e : 0.2f * e;
        m = fmaxf(m, e);
    }
#pragma unroll
    for (int t = 32; t; t >>= 1) m = fmaxf(m, __shfl_xor(m, t));
    float z = 0.f;
    for (int j = lane; j < n; j += 64) {
        float e = asrc[ssrc[o + j]] + ad;
        e = e > 0.f ? e : 0.2f * e;
        z += expf(e - m);
    }
#pragma unroll
    for (int t = 32; t; t >>= 1) z += __shfl_xor(z, t);
    float zinv = 1.0f / (z + 1e-16f);

    float4 acc = {0.f, 0.f, 0.f, 0.f};
    int j = 0;
    for (; j + 2 <= n; j += 2) {
        int s0 = ssrc[o + j], s1 = ssrc[o + j + 1];
        const ushort4 h0 = *reinterpret_cast<const ushort4*>(&h[(long)s0 * HID + lane * 4]);
        const ushort4 h1 = *reinterpret_cast<const ushort4*>(&h[(long)s1 * HID + lane * 4]);
        float e0 = asrc[s0] + ad; e0 = e0 > 0.f ? e0 : 0.2f * e0;
        float e1 = asrc[s1] + ad; e1 = e1 > 0.f ? e1 : 0.2f * e1;
        float a0 = expf(e0 - m) * zinv;
        float a1 = expf(e1 - m) * zinv;
        acc.x += a0 * bf2f(h0.x) + a1 * bf2f(h1.x);
        acc.y += a0 * bf2f(h0.y) + a1 * bf2f(h1.y);
        acc.z += a0 * bf2f(h0.z) + a1 * bf2f(h1.z);
        acc.w += a0 * bf2f(h0.w) + a1 * bf2f(h1.w);
    }
    if (j < n) {
        int s0 = ssrc[o + j];
        const ushort4 h0 = *reinterpret_cast<const ushort4*>(&h[(long)s0 * HID + lane * 4]);
        float e0 = asrc[s0] + ad; e0 = e0 > 0.f ? e0 : 0.2f * e0;
        float a0 = expf(e0 - m) * zinv;
        acc.x += a0 * bf2f(h0.x); acc.y += a0 * bf2f(h0.y);
        acc.z += a0 * bf2f(h0.z); acc.w += a0 * bf2f(h0.w);
    }
    ushort4 r;
    r.x = (unsigned short)f2bf(acc.x > 0.f ? acc.x : expm1f(acc.x));
    r.y = (unsigned short)f2bf(acc.y > 0.f ? acc.y : expm1f(acc.y));
    r.z = (unsigned short)f2bf(acc.z > 0.f ? acc.z : expm1f(acc.z));
    r.w = (unsigned short)f2bf(acc.w > 0.f ? acc.w : expm1f(acc.w));
    *reinterpret_cast<ushort4*>(&gat2[(long)d * HID + lane * 4]) = r;
}

// ---------------- batchnorm ----------------------------------------------------------------
__global__ void bn_partial(const float* __restrict__ zd, float* __restrict__ s,
                           float* __restrict__ sq) {
    int t = threadIdx.x;
    float a = 0.f, b = 0.f;
    int r0 = blockIdx.x * 128;
    for (int r = r0; r < r0 + 128; ++r) {
        float v = zd[(long)r * HID + t];
        a += v;
        b += v * v;
    }
    atomicAdd(&s[t], a);
    atomicAdd(&sq[t], b);
}

__global__ void bn_finalize(const float* __restrict__ s, const float* __restrict__ sq,
                            const float* __restrict__ gamma, const float* __restrict__ beta,
                            float* __restrict__ scale, float* __restrict__ shift) {
    int t = threadIdx.x;
    float mean = s[t] / (float)NN;
    float var  = sq[t] / (float)NN - mean * mean;
    float sc   = gamma[t] * rsqrtf(var + 1e-5f);
    scale[t] = sc;
    shift[t] = beta[t] - mean * sc;
}

__global__ void bn_apply_elu_bf(const float* __restrict__ zd, const float* __restrict__ scale,
                                const float* __restrict__ shift, unsigned short* __restrict__ zb) {
    for (long i = (long)blockIdx.x * blockDim.x + threadIdx.x; i < (long)NN * HID;
         i += (long)gridDim.x * blockDim.x) {
        int c = (int)(i & 255);
        float v = zd[i] * scale[c] + shift[c];
        v = v > 0.f ? v : expm1f(v);
        zb[i] = (unsigned short)f2bf(v);
    }
}

// ---------------- fused readout-norm + discriminator ---------------------------------------
// block = node r, 128 threads. vsum_part 4x[8192][128], rowsum_part 4x[8192].
__global__ void readout_disc(const float* __restrict__ vsum_part,
                             const float* __restrict__ rowsum_part,
                             const float* __restrict__ h2f,
                             const float* __restrict__ W, const float* __restrict__ b,
                             float* __restrict__ ret, float* __restrict__ reta) {
    __shared__ float gg[128];
    int r = blockIdx.x, t = threadIdx.x;
    float rs = 0.f, v = 0.f;
#pragma unroll
    for (int kc = 0; kc < 4; ++kc) {
        rs += rowsum_part[(long)kc * NN + r];
        v  += vsum_part[((long)kc * NN + r) * 128 + t];
    }
    v /= rs;
    int w = t >> 6, lane = t & 63;
    float sq = v * v;
#pragma unroll
    for (int off = 32; off > 0; off >>= 1) sq += __shfl_xor(sq, off);
    float nrm = fmaxf(sqrtf(sq), 1e-12f);
    gg[t] = 1.0f / (1.0f + expf(-(v / nrm)));
    __syncthreads();
    // wave 0: ret (c=g, hp=h2, hm=h2a); wave 1: reta (c=ga, hp=h2a, hm=h2)
    const float* hp_base = h2f + (w ? 524288 : 0);
    const float* hm_base = h2f + (w ? 0 : 524288);
    float u = 0.f;
#pragma unroll 8
    for (int e = 0; e < 64; ++e) u += W[lane * 64 + e] * gg[w * 64 + e];
    float hp = hp_base[(long)r * 64 + lane];
    float hm = hm_base[(long)r * 64 + lane];
    float t1 = hp * u, t2 = hm * u;
#pragma unroll
    for (int off = 32; off > 0; off >>= 1) {
        t1 += __shfl_xor(t1, off);
        t2 += __shfl_xor(t2, off);
    }
    if (lane == 0) {
        float bb = b[0];
        float* dstp = w ? reta : ret;
        dstp[r * 2]     = t1 + bb;
        dstp[r * 2 + 1] = t2 + bb;
    }
}

// ---------------- driver -------------------------------------------------------------------
extern "C" void kernel_launch(void* const* d_in, const int* in_sizes, int n_in,
                              void* d_out, int out_size, void* d_ws, size_t ws_size,
                              hipStream_t stream) {
    const float* feat    = (const float*)d_in[0];
    const float* feat_a  = (const float*)d_in[1];
    const float* gneigh  = (const float*)d_in[2];
    const float* W1      = (const float*)d_in[3];
    const float* att_src = (const float*)d_in[4];
    const float* att_dst = (const float*)d_in[5];
    const float* W2      = (const float*)d_in[6];
    const float* Wd1     = (const float*)d_in[7];
    const float* bd1     = (const float*)d_in[8];
    const float* gamma   = (const float*)d_in[9];
    const float* beta    = (const float*)d_in[10];
    const float* Wd2     = (const float*)d_in[11];
    const float* bd2     = (const float*)d_in[12];
    const float* disc_W  = (const float*)d_in[13];
    const float* disc_b  = (const float*)d_in[14];
    const int*   eidx    = (const int*)d_in[15];
    const int*   src = eidx;
    const int*   dst = eidx + EE;
    float* out = (float*)d_out;

    // workspace layout (floats)
    float* w = (float*)d_ws;
    unsigned short* h_bf2  = (unsigned short*)w;                   // [2][8192][256] bf16 = 2097152 f
    unsigned short* gat_bf2 = (unsigned short*)(w + 2097152);      // [2][8192][256] bf16 = 2097152 f
    float* zdec    = w + 4194304;                                  // [8192][256] f32 = 2097152 f
    unsigned short* zdec_bf = (unsigned short*)(zdec + 2097152);   // 1048576 f
    float* h2f     = zdec + 2097152 + 1048576;                     // [2][8192][64] = 1048576 f
    unsigned short* h2b = (unsigned short*)(h2f + 1048576);        // [8192][64] bf16 = 262144 f
    unsigned short* HT  = h2b + 524288;                            // [128][8192] bf16 = 524288 f
    float* asrc2   = (float*)(HT + 1048576);                       // 16384
    float* adst2   = asrc2 + 16384;                                // 16384
    float* bnsum   = adst2 + 16384;           // 256
    float* bnsq    = bnsum + 256;             // 256
    float* scale   = bnsq + 256;              // 256
    float* shift   = scale + 256;             // 256
    unsigned short* W1t  = (unsigned short*)(shift + 256);         // 770048 sh
    unsigned short* W2t  = W1t + 770048;                           // 16384 sh
    unsigned short* Wd1t = W2t + 16384;                            // 16384 sh
    unsigned short* Wd2t = Wd1t + 16384;                           // 786432 sh
    int*   ideg    = (int*)(Wd2t + 786432);   // 8192
    int*   ioff    = ideg + 8192;             // 8192
    int*   icur    = ioff + 8192;             // 8192
    int*   issrc   = icur + 8192;             // 262144
    // readout-phase reuse: h_bf2 + gat_bf2 (dead after w2_gemm) -> vsum partials (16 MB)
    float* vsum_part = w;                     // 4*8192*128 = 4194304 f
    float* rowsum_part = zdec;                // 4*8192 = 32768 f (zdec dead after bn_apply)

    // ---- one-time weight conversions
    cvt_W1t<<<3008, 256, 0, stream>>>(W1, W1t);
    cvt_W2t<<<64, 256, 0, stream>>>(W2, W2t);
    cvt_Wd1t<<<64, 256, 0, stream>>>(Wd1, Wd1t);
    cvt_Wd2t<<<3072, 256, 0, stream>>>(Wd2, Wd2t);

    // ---- CSR build
    hipMemsetAsync(ideg, 0, 8192 * 4, stream);
    deg_count<<<EE / 256, 256, 0, stream>>>(dst, ideg);
    scan_offsets<<<1, 256, 0, stream>>>(ideg, ioff, icur);
    scatter_edges<<<EE / 256, 256, 0, stream>>>(src, dst, icur, issrc);

    // ---- encoder (both passes batched)
    feat_gemm<<<256, 256, 0, stream>>>(feat, feat_a, W1t, h_bf2);
    attn_coeff_bf<<<4096, 256, 0, stream>>>(h_bf2, att_src, att_dst, asrc2, adst2);
    gat_gather<<<4096, 256, 0, stream>>>(issrc, ioff, ideg, asrc2, adst2, h_bf2, gat_bf2);
    w2_gemm<<<dim3(1, 256), 256, 0, stream>>>(gat_bf2, W2t, h2f, h2b, HT, out);

    // ---- decoder: h3 = elu(BN(h2 @ Wd1 + bd1)) @ Wd2 + bd2
    wd1_gemm<<<dim3(4, 128), 256, 0, stream>>>(h2b, Wd1t, bd1, zdec);
    hipMemsetAsync(bnsum, 0, 512 * 4, stream);
    bn_partial<<<64, 256, 0, stream>>>(zdec, bnsum, bnsq);
    bn_finalize<<<1, 256, 0, stream>>>(bnsum, bnsq, gamma, beta, scale, shift);
    bn_apply_elu_bf<<<2048, 256, 0, stream>>>(zdec, scale, shift, zdec_bf);
    wd2_gemm<<<dim3(24, 64), 256, 0, stream>>>(zdec_bf, Wd2t, bd2, out + O_H3);

    // ---- readout + discriminator (vsum over h_bf2/gat_bf2, rowsum over zdec — both dead)
    readout_mfma2<<<dim3(128, 4), 256, 0, stream>>>(gneigh, HT, vsum_part, rowsum_part);
    readout_disc<<<8192, 128, 0, stream>>>(vsum_part, rowsum_part, h2f, disc_W, disc_b,
                                           out + O_RET, out + O_RETA);
}

// Round 12
// 400.001 us; speedup vs baseline: 1.1244x; 1.0487x over previous
//
#include <hip/hip_runtime.h>
#include <hip/hip_bf16.h>
#include <math.h>

// Problem dims
constexpr int NN  = 8192;
constexpr int EE  = 262144;
constexpr int IN  = 3000;
constexpr int INP = 3008;   // IN padded to mult of 64
constexpr int HID = 256;
constexpr int OUT = 64;

// Output offsets (floats) in d_out: (h2, h3, ret, ret_a, h2, h2_a)
constexpr long O_H2   = 0;
constexpr long O_H3   = 524288;          // 8192*64
constexpr long O_RET  = 25100288;        // + 8192*3000
constexpr long O_RETA = 25116672;        // + 8192*2
constexpr long O_H2B  = 25133056;        // + 8192*2
constexpr long O_H2A  = 25657344;        // + 8192*64

typedef __attribute__((ext_vector_type(8))) short short8v;   // 8 bf16 (4 VGPRs)
typedef __attribute__((ext_vector_type(4))) float f32x4;     // MFMA accumulator

__device__ __forceinline__ short f2bf(float f) {   // RNE f32 -> bf16 bits
    unsigned u = __float_as_uint(f);
    return (short)((u + 0x7FFF + ((u >> 16) & 1)) >> 16);
}
__device__ __forceinline__ float bf2f(unsigned short u) {
    return __uint_as_float(((unsigned)u) << 16);
}

// ================= conversion kernels (one-time per launch) ================================
__global__ void cvt_W1t(const float* __restrict__ W, unsigned short* __restrict__ Wt) {
    int i = blockIdx.x * 256 + threadIdx.x;            // over 256*3008
    int n = i / INP, k = i % INP;
    Wt[i] = (k < IN) ? (unsigned short)f2bf(W[(long)k * HID + n]) : 0;
}
__global__ void cvt_W2t(const float* __restrict__ W, unsigned short* __restrict__ Wt) {
    int i = blockIdx.x * 256 + threadIdx.x;            // over 64*256
    int n = i / HID, k = i % HID;
    Wt[i] = (unsigned short)f2bf(W[(long)k * OUT + n]);
}
__global__ void cvt_Wd1t(const float* __restrict__ W, unsigned short* __restrict__ Wt) {
    int i = blockIdx.x * 256 + threadIdx.x;            // over 256*64
    int n = i / OUT, k = i % OUT;
    Wt[i] = (unsigned short)f2bf(W[(long)k * HID + n]);
}
__global__ void cvt_Wd2t(const float* __restrict__ W, unsigned short* __restrict__ Wt) {
    int i = blockIdx.x * 256 + threadIdx.x;            // over 3072*256
    int n = i / HID, k = i % HID;
    Wt[i] = (n < IN) ? (unsigned short)f2bf(W[(long)k * IN + n]) : 0;
}

// ================= feat GEMM: [feat;feat_a][16384,3000] @ W1 -> partials ===================
// 128x128 tile, BK=64, reg-prefetch, f32 A converted during staging.
// Split-K=4: blockIdx.z = chunk (12/12/12/11 K-tiles); partials Cpart[z][16384][256] f32.
// grid dim3(2, 128, 4) = 1024 blocks = 4 blocks/CU -> 16 waves/CU for latency hiding.
__global__ __launch_bounds__(256) void feat_gemm(const float* __restrict__ A0,
                                                 const float* __restrict__ A1,
                                                 const unsigned short* __restrict__ Bt,
                                                 float* __restrict__ Cpart) {
    __shared__ unsigned short As[128][72];
    __shared__ unsigned short Bs[128][72];
    int xb = blockIdx.x, yb = blockIdx.y;   // col-tile 0..1, row-tile 0..127 (both passes)
    int pass = yb >> 6;
    int row0 = (yb & 63) * 128, col0 = xb * 128;
    const float* A = pass ? A1 : A0;
    int t = threadIdx.x, w = t >> 6, l = t & 63;
    int sr = t >> 1, sh = (t & 1) * 32;
    int wm = (w >> 1) * 64, wn = (w & 1) * 64;
    int fr = l & 15, fq = l >> 4;
    const unsigned short* Bp = Bt + (long)(col0 + sr) * INP + sh;
    const float* Arow = A + (long)(row0 + sr) * IN;

    int tb = blockIdx.z * 12;               // first K-tile of this chunk
    int ktiles = min(12, 47 - tb);          // 12,12,12,11

    float4  paf[8];
    short8v pb[4];
    auto loadA = [&](int k0) {
        const float* Ar = Arow + k0 + sh;
        if (k0 + 64 <= IN) {
#pragma unroll
            for (int q = 0; q < 8; ++q) paf[q] = *reinterpret_cast<const float4*>(Ar + q * 4);
        } else {
#pragma unroll
            for (int q = 0; q < 8; ++q) {
                int kb = k0 + sh + q * 4;
                float4 v;
                v.x = (kb + 0 < IN) ? Ar[q * 4 + 0] : 0.f;
                v.y = (kb + 1 < IN) ? Ar[q * 4 + 1] : 0.f;
                v.z = (kb + 2 < IN) ? Ar[q * 4 + 2] : 0.f;
                v.w = (kb + 3 < IN) ? Ar[q * 4 + 3] : 0.f;
                paf[q] = v;
            }
        }
    };
    auto loadB = [&](int k0) {
#pragma unroll
        for (int q = 0; q < 4; ++q) pb[q] = *reinterpret_cast<const short8v*>(Bp + k0 + q * 8);
    };
    loadA(tb * 64); loadB(tb * 64);

    f32x4 acc[4][4] = {};
    for (int tt = 0; tt < ktiles; ++tt) {
#pragma unroll
        for (int q = 0; q < 4; ++q) {
            float4 v0 = paf[q * 2], v1 = paf[q * 2 + 1];
            short8v s;
            s[0]=f2bf(v0.x); s[1]=f2bf(v0.y); s[2]=f2bf(v0.z); s[3]=f2bf(v0.w);
            s[4]=f2bf(v1.x); s[5]=f2bf(v1.y); s[6]=f2bf(v1.z); s[7]=f2bf(v1.w);
            *reinterpret_cast<short8v*>(&As[sr][sh + q * 8]) = s;
        }
#pragma unroll
        for (int q = 0; q < 4; ++q)
            *reinterpret_cast<short8v*>(&Bs[sr][sh + q * 8]) = pb[q];
        __syncthreads();
        if (tt + 1 < ktiles) {
            int k0 = (tb + tt + 1) * 64;
            loadA(k0); loadB(k0);
        }
#pragma unroll
        for (int kk = 0; kk < 2; ++kk) {
            short8v fa[4], fb[4];
#pragma unroll
            for (int i = 0; i < 4; ++i)
                fa[i] = *reinterpret_cast<const short8v*>(&As[wm + i * 16 + fr][kk * 32 + fq * 8]);
#pragma unroll
            for (int j = 0; j < 4; ++j)
                fb[j] = *reinterpret_cast<const short8v*>(&Bs[wn + j * 16 + fr][kk * 32 + fq * 8]);
#pragma unroll
            for (int i = 0; i < 4; ++i)
#pragma unroll
                for (int j = 0; j < 4; ++j)
                    acc[i][j] = __builtin_amdgcn_mfma_f32_16x16x32_bf16(fa[i], fb[j], acc[i][j], 0, 0, 0);
        }
        __syncthreads();
    }
    int dc = l & 15;
    long zbase = (long)blockIdx.z * 16384 * 256;
    long rbase = (long)(pass * NN + row0) * 256;
#pragma unroll
    for (int i = 0; i < 4; ++i)
#pragma unroll
        for (int j = 0; j < 4; ++j) {
            int c = col0 + wn + j * 16 + dc;
#pragma unroll
            for (int q = 0; q < 4; ++q) {
                int r = wm + i * 16 + fq * 4 + q;
                Cpart[zbase + rbase + (long)r * 256 + c] = acc[i][j][q];
            }
        }
}

// sum 4 split-K partials, emit bf16 h. grid 4096 x 256, 4 floats/thread.
__global__ void reduce_cvt4(const float* __restrict__ p, unsigned short* __restrict__ hb) {
    long i4 = ((long)blockIdx.x * 256 + threadIdx.x) * 4;     // over 16384*256
    float4 a = *reinterpret_cast<const float4*>(p + i4);
    float4 b = *reinterpret_cast<const float4*>(p + 4194304 + i4);
    float4 c = *reinterpret_cast<const float4*>(p + 8388608 + i4);
    float4 d = *reinterpret_cast<const float4*>(p + 12582912 + i4);
    ushort4 r;
    r.x = (unsigned short)f2bf(a.x + b.x + c.x + d.x);
    r.y = (unsigned short)f2bf(a.y + b.y + c.y + d.y);
    r.z = (unsigned short)f2bf(a.z + b.z + c.z + d.z);
    r.w = (unsigned short)f2bf(a.w + b.w + c.w + d.w);
    *reinterpret_cast<ushort4*>(hb + i4) = r;
}

// ================= W2 GEMM with mega-epilogue ==============================================
__global__ __launch_bounds__(256) void w2_gemm(const unsigned short* __restrict__ A,
                                               const unsigned short* __restrict__ Bt,
                                               float* __restrict__ h2f,
                                               unsigned short* __restrict__ h2b,
                                               unsigned short* __restrict__ HT,
                                               float* __restrict__ out) {
    __shared__ unsigned short As[64][72];
    __shared__ unsigned short Bs[64][72];
    int t = threadIdx.x, w = t >> 6, l = t & 63;
    int row0 = blockIdx.y * 64;
    int srow = t >> 2, scol = (t & 3) * 16;
    const unsigned short* Ap = A + (long)(row0 + srow) * HID + scol;
    const unsigned short* Bp = Bt + (long)srow * HID + scol;   // 64 rows only
    int wm = (w >> 1) * 32, wn = (w & 1) * 32;
    int fr = l & 15, fq = l >> 4;

    short8v a0r, a1r, b0r, b1r;
    a0r = *reinterpret_cast<const short8v*>(Ap);
    a1r = *reinterpret_cast<const short8v*>(Ap + 8);
    b0r = *reinterpret_cast<const short8v*>(Bp);
    b1r = *reinterpret_cast<const short8v*>(Bp + 8);

    f32x4 acc[2][2] = {};
    for (int tt = 0; tt < 4; ++tt) {
        *reinterpret_cast<short8v*>(&As[srow][scol])     = a0r;
        *reinterpret_cast<short8v*>(&As[srow][scol + 8]) = a1r;
        *reinterpret_cast<short8v*>(&Bs[srow][scol])     = b0r;
        *reinterpret_cast<short8v*>(&Bs[srow][scol + 8]) = b1r;
        __syncthreads();
        if (tt + 1 < 4) {
            const unsigned short* Ap2 = Ap + (tt + 1) * 64;
            const unsigned short* Bp2 = Bp + (tt + 1) * 64;
            a0r = *reinterpret_cast<const short8v*>(Ap2);
            a1r = *reinterpret_cast<const short8v*>(Ap2 + 8);
            b0r = *reinterpret_cast<const short8v*>(Bp2);
            b1r = *reinterpret_cast<const short8v*>(Bp2 + 8);
        }
#pragma unroll
        for (int kk = 0; kk < 2; ++kk) {
            short8v fa0 = *reinterpret_cast<const short8v*>(&As[wm + fr][kk * 32 + fq * 8]);
            short8v fa1 = *reinterpret_cast<const short8v*>(&As[wm + 16 + fr][kk * 32 + fq * 8]);
            short8v fb0 = *reinterpret_cast<const short8v*>(&Bs[wn + fr][kk * 32 + fq * 8]);
            short8v fb1 = *reinterpret_cast<const short8v*>(&Bs[wn + 16 + fr][kk * 32 + fq * 8]);
            acc[0][0] = __builtin_amdgcn_mfma_f32_16x16x32_bf16(fa0, fb0, acc[0][0], 0, 0, 0);
            acc[0][1] = __builtin_amdgcn_mfma_f32_16x16x32_bf16(fa0, fb1, acc[0][1], 0, 0, 0);
            acc[1][0] = __builtin_amdgcn_mfma_f32_16x16x32_bf16(fa1, fb0, acc[1][0], 0, 0, 0);
            acc[1][1] = __builtin_amdgcn_mfma_f32_16x16x32_bf16(fa1, fb1, acc[1][1], 0, 0, 0);
        }
        __syncthreads();
    }
    int dc = l & 15;
    int pass = row0 >> 13;
#pragma unroll
    for (int i = 0; i < 2; ++i)
#pragma unroll
        for (int j = 0; j < 2; ++j) {
            int c = wn + j * 16 + dc;
#pragma unroll
            for (int q = 0; q < 4; ++q) {
                int r = row0 + wm + i * 16 + fq * 4 + q;
                int n = r & 8191;
                float v = acc[i][j][q];
                unsigned short vb = (unsigned short)f2bf(v);
                h2f[(long)pass * 524288 + (long)n * 64 + c] = v;
                if (pass == 0) {
                    out[O_H2  + (long)n * 64 + c] = v;
                    out[O_H2B + (long)n * 64 + c] = v;
                    h2b[(long)n * 64 + c] = vb;
                } else {
                    out[O_H2A + (long)n * 64 + c] = v;
                }
                HT[(long)(pass * 64 + c) * NN + n] = vb;
            }
        }
}

// ================= 128x128 bf16 GEMM (Wd2) ================================================
__global__ __launch_bounds__(256) void wd2_gemm(const unsigned short* __restrict__ A,
                                                const unsigned short* __restrict__ Bt,
                                                const float* __restrict__ bias,
                                                float* __restrict__ Cf) {
    __shared__ unsigned short As[128][72];
    __shared__ unsigned short Bs[128][72];
    int t = threadIdx.x, w = t >> 6, l = t & 63;
    int row0 = blockIdx.y * 128, col0 = blockIdx.x * 128;
    int sr = t >> 1, sh = (t & 1) * 32;
    int wm = (w >> 1) * 64, wn = (w & 1) * 64;
    int fr = l & 15, fq = l >> 4;
    const unsigned short* Ap = A  + (long)(row0 + sr) * HID + sh;
    const unsigned short* Bp = Bt + (long)(col0 + sr) * HID + sh;

    short8v pa[4], pb[4];
#pragma unroll
    for (int q = 0; q < 4; ++q) pa[q] = *reinterpret_cast<const short8v*>(Ap + q * 8);
#pragma unroll
    for (int q = 0; q < 4; ++q) pb[q] = *reinterpret_cast<const short8v*>(Bp + q * 8);

    f32x4 acc[4][4] = {};
    for (int tt = 0; tt < 4; ++tt) {
#pragma unroll
        for (int q = 0; q < 4; ++q) {
            *reinterpret_cast<short8v*>(&As[sr][sh + q * 8]) = pa[q];
            *reinterpret_cast<short8v*>(&Bs[sr][sh + q * 8]) = pb[q];
        }
        __syncthreads();
        if (tt + 1 < 4) {
            int k0 = (tt + 1) * 64;
#pragma unroll
            for (int q = 0; q < 4; ++q) pa[q] = *reinterpret_cast<const short8v*>(Ap + k0 + q * 8);
#pragma unroll
            for (int q = 0; q < 4; ++q) pb[q] = *reinterpret_cast<const short8v*>(Bp + k0 + q * 8);
        }
#pragma unroll
        for (int kk = 0; kk < 2; ++kk) {
            short8v fa[4], fb[4];
#pragma unroll
            for (int i = 0; i < 4; ++i)
                fa[i] = *reinterpret_cast<const short8v*>(&As[wm + i * 16 + fr][kk * 32 + fq * 8]);
#pragma unroll
            for (int j = 0; j < 4; ++j)
                fb[j] = *reinterpret_cast<const short8v*>(&Bs[wn + j * 16 + fr][kk * 32 + fq * 8]);
#pragma unroll
            for (int i = 0; i < 4; ++i)
#pragma unroll
                for (int j = 0; j < 4; ++j)
                    acc[i][j] = __builtin_amdgcn_mfma_f32_16x16x32_bf16(fa[i], fb[j], acc[i][j], 0, 0, 0);
        }
        __syncthreads();
    }
    int dc = l & 15;
#pragma unroll
    for (int i = 0; i < 4; ++i)
#pragma unroll
        for (int j = 0; j < 4; ++j) {
            int c = col0 + wn + j * 16 + dc;
            if (c < IN) {
                float bb = bias[c];
#pragma unroll
                for (int q = 0; q < 4; ++q) {
                    int r = row0 + wm + i * 16 + fq * 4 + q;
                    Cf[(long)r * IN + c] = acc[i][j][q] + bb;
                }
            }
        }
}

// ================= 64x64 bf16 GEMM (Wd1) ===================================================
__global__ __launch_bounds__(256) void wd1_gemm(const unsigned short* __restrict__ A,
                                                const unsigned short* __restrict__ Bt,
                                                const float* __restrict__ bias,
                                                float* __restrict__ C) {
    __shared__ unsigned short As[64][72];
    __shared__ unsigned short Bs[64][72];
    int t = threadIdx.x, w = t >> 6, l = t & 63;
    int row0 = blockIdx.y * 64, col0 = blockIdx.x * 64;
    int srow = t >> 2, scol = (t & 3) * 16;
    const unsigned short* Ap = A  + (long)(row0 + srow) * OUT + scol;   // K=64
    const unsigned short* Bp = Bt + (long)(col0 + srow) * OUT + scol;
    int wm = (w >> 1) * 32, wn = (w & 1) * 32;
    int fr = l & 15, fq = l >> 4;

    *reinterpret_cast<short8v*>(&As[srow][scol])     = *reinterpret_cast<const short8v*>(Ap);
    *reinterpret_cast<short8v*>(&As[srow][scol + 8]) = *reinterpret_cast<const short8v*>(Ap + 8);
    *reinterpret_cast<short8v*>(&Bs[srow][scol])     = *reinterpret_cast<const short8v*>(Bp);
    *reinterpret_cast<short8v*>(&Bs[srow][scol + 8]) = *reinterpret_cast<const short8v*>(Bp + 8);
    __syncthreads();
    f32x4 acc[2][2] = {};
#pragma unroll
    for (int kk = 0; kk < 2; ++kk) {
        short8v fa0 = *reinterpret_cast<const short8v*>(&As[wm + fr][kk * 32 + fq * 8]);
        short8v fa1 = *reinterpret_cast<const short8v*>(&As[wm + 16 + fr][kk * 32 + fq * 8]);
        short8v fb0 = *reinterpret_cast<const short8v*>(&Bs[wn + fr][kk * 32 + fq * 8]);
        short8v fb1 = *reinterpret_cast<const short8v*>(&Bs[wn + 16 + fr][kk * 32 + fq * 8]);
        acc[0][0] = __builtin_amdgcn_mfma_f32_16x16x32_bf16(fa0, fb0, acc[0][0], 0, 0, 0);
        acc[0][1] = __builtin_amdgcn_mfma_f32_16x16x32_bf16(fa0, fb1, acc[0][1], 0, 0, 0);
        acc[1][0] = __builtin_amdgcn_mfma_f32_16x16x32_bf16(fa1, fb0, acc[1][0], 0, 0, 0);
        acc[1][1] = __builtin_amdgcn_mfma_f32_16x16x32_bf16(fa1, fb1, acc[1][1], 0, 0, 0);
    }
    int dc = l & 15;
#pragma unroll
    for (int i = 0; i < 2; ++i)
#pragma unroll
        for (int j = 0; j < 2; ++j) {
            int c = col0 + wn + j * 16 + dc;
            float bb = bias[c];
#pragma unroll
            for (int q = 0; q < 4; ++q) {
                int r = row0 + wm + i * 16 + fq * 4 + q;
                C[(long)r * HID + c] = acc[i][j][q] + bb;
            }
        }
}

// ---------------- readout MFMA: prefetched, transposed-B -----------------------------------
__global__ __launch_bounds__(256) void readout_mfma2(const float* __restrict__ gn,
                                                     const unsigned short* __restrict__ HT,
                                                     float* __restrict__ vsum_part,
                                                     float* __restrict__ rowsum_part) {
    __shared__ unsigned short As[64][72];
    __shared__ unsigned short Bs[128][72];
    __shared__ float rsacc[64][4];
    int t = threadIdx.x, w = t >> 6, l = t & 63;
    int row0 = blockIdx.x * 64;
    int kc = blockIdx.y, kbeg = kc * 2048;
    int asr = t >> 2, asc = (t & 3) * 16;
    int bsr = t >> 1, bsc = (t & 1) * 32;
    const float*          Ap = gn + (long)(row0 + asr) * NN + kbeg + asc;
    const unsigned short* Bp = HT + (long)bsr * NN + kbeg + bsc;
    int wm = (w >> 1) * 32, wn = (w & 1) * 64;
    int fr = l & 15, fq = l >> 4;

    float4  a4[4];
    short8v b8[4];
#pragma unroll
    for (int q = 0; q < 4; ++q) a4[q] = *reinterpret_cast<const float4*>(Ap + q * 4);
#pragma unroll
    for (int q = 0; q < 4; ++q) b8[q] = *reinterpret_cast<const short8v*>(Bp + q * 8);

    f32x4 acc[2][4] = {};
    float myrs = 0.f;
    for (int it = 0; it < 32; ++it) {
#pragma unroll
        for (int q = 0; q < 4; ++q) {
            float4 v = a4[q];
            ushort4 s;
            s.x = (unsigned short)f2bf(v.x);
            s.y = (unsigned short)f2bf(v.y);
            s.z = (unsigned short)f2bf(v.z);
            s.w = (unsigned short)f2bf(v.w);
            *reinterpret_cast<ushort4*>(&As[asr][asc + q * 4]) = s;
            myrs += v.x + v.y + v.z + v.w;
        }
#pragma unroll
        for (int q = 0; q < 4; ++q)
            *reinterpret_cast<short8v*>(&Bs[bsr][bsc + q * 8]) = b8[q];
        __syncthreads();
        if (it + 1 < 32) {
            const float*          Ap2 = Ap + (it + 1) * 64;
            const unsigned short* Bp2 = Bp + (it + 1) * 64;
#pragma unroll
            for (int q = 0; q < 4; ++q) a4[q] = *reinterpret_cast<const float4*>(Ap2 + q * 4);
#pragma unroll
            for (int q = 0; q < 4; ++q) b8[q] = *reinterpret_cast<const short8v*>(Bp2 + q * 8);
        }
#pragma unroll
        for (int kk = 0; kk < 2; ++kk) {
            short8v fa0 = *reinterpret_cast<const short8v*>(&As[wm + fr][kk * 32 + fq * 8]);
            short8v fa1 = *reinterpret_cast<const short8v*>(&As[wm + 16 + fr][kk * 32 + fq * 8]);
#pragma unroll
            for (int j = 0; j < 4; ++j) {
                short8v fb = *reinterpret_cast<const short8v*>(&Bs[wn + j * 16 + fr][kk * 32 + fq * 8]);
                acc[0][j] = __builtin_amdgcn_mfma_f32_16x16x32_bf16(fa0, fb, acc[0][j], 0, 0, 0);
                acc[1][j] = __builtin_amdgcn_mfma_f32_16x16x32_bf16(fa1, fb, acc[1][j], 0, 0, 0);
            }
        }
        __syncthreads();
    }
    rsacc[asr][t & 3] = myrs;
    __syncthreads();
    if (t < 64)
        rowsum_part[(long)kc * NN + row0 + t] =
            rsacc[t][0] + rsacc[t][1] + rsacc[t][2] + rsacc[t][3];
    int dc = l & 15;
#pragma unroll
    for (int i = 0; i < 2; ++i)
#pragma unroll
        for (int j = 0; j < 4; ++j) {
            int c = wn + j * 16 + dc;
#pragma unroll
            for (int q = 0; q < 4; ++q) {
                int r = row0 + wm + i * 16 + fq * 4 + q;
                vsum_part[((long)kc * NN + r) * 128 + c] = acc[i][j][q];
            }
        }
}

// ---------------- CSR build ----------------------------------------------------------------
__global__ void deg_count(const int* __restrict__ dst, int* __restrict__ deg) {
    int i = blockIdx.x * 256 + threadIdx.x;
    if (i < EE) atomicAdd(&deg[dst[i]], 1);
}

__global__ __launch_bounds__(256) void scan_offsets(const int* __restrict__ deg,
                                                    int* __restrict__ off,
                                                    int* __restrict__ cursor) {
    __shared__ int part[256];
    int t = threadIdx.x;
    int base = t * 32;
    int local[32];
    int s = 0;
#pragma unroll
    for (int i = 0; i < 32; ++i) { local[i] = s; s += deg[base + i]; }
    part[t] = s;
    __syncthreads();
    for (int o2 = 1; o2 < 256; o2 <<= 1) {
        int v = (t >= o2) ? part[t - o2] : 0;
        __syncthreads();
        part[t] += v;
        __syncthreads();
    }
    int pre = (t == 0) ? 0 : part[t - 1];
#pragma unroll
    for (int i = 0; i < 32; ++i) {
        int v = pre + local[i];
        off[base + i] = v;
        cursor[base + i] = v;
    }
}

__global__ void scatter_edges(const int* __restrict__ src, const int* __restrict__ dst,
                              int* __restrict__ cursor, int* __restrict__ ssrc) {
    int i = blockIdx.x * 256 + threadIdx.x;
    if (i >= EE) return;
    int slot = atomicAdd(&cursor[dst[i]], 1);
    ssrc[slot] = src[i];
}

// ---------------- attention coefficients (batched both passes) -----------------------------
__global__ void attn_coeff_bf(const unsigned short* __restrict__ h,
                              const float* __restrict__ att_src,
                              const float* __restrict__ att_dst,
                              float* __restrict__ a_src, float* __restrict__ a_dst) {
    int wave = threadIdx.x >> 6, lane = threadIdx.x & 63;
    int n = blockIdx.x * 4 + wave;      // 0..16383
    ushort4 hv = *reinterpret_cast<const ushort4*>(&h[(long)n * HID + lane * 4]);
    float4 vs = *reinterpret_cast<const float4*>(&att_src[lane * 4]);
    float4 vd = *reinterpret_cast<const float4*>(&att_dst[lane * 4]);
    float h0 = bf2f(hv.x), h1 = bf2f(hv.y), h2v = bf2f(hv.z), h3v = bf2f(hv.w);
    float s1 = h0 * vs.x + h1 * vs.y + h2v * vs.z + h3v * vs.w;
    float s2 = h0 * vd.x + h1 * vd.y + h2v * vd.z + h3v * vd.w;
#pragma unroll
    for (int off = 32; off > 0; off >>= 1) {
        s1 += __shfl_down(s1, off);
        s2 += __shfl_down(s2, off);
    }
    if (lane == 0) { a_src[n] = s1; a_dst[n] = s2; }
}

// ---------------- fused GAT gather (batched both passes) -----------------------------------
__global__ __launch_bounds__(256) void gat_gather(const int* __restrict__ ssrc,
                                                  const int* __restrict__ off,
                                                  const int* __restrict__ deg,
                                                  const float* __restrict__ asrc2,
                                                  const float* __restrict__ adst2,
                                                  const unsigned short* __restrict__ hb2,
                                                  unsigned short* __restrict__ gat2) {
    int wv = threadIdx.x >> 6, lane = threadIdx.x & 63;
    int d = blockIdx.x * 4 + wv;        // 0..16383
    int pass = d >> 13, node = d & 8191;
    const float* asrc = asrc2 + pass * NN;
    const unsigned short* h = hb2 + (long)pass * NN * HID;
    int o = off[node], n = deg[node];
    float ad = adst2[d];

    float m = -INFINITY;
    for (int j = lane; j < n; j += 64) {
        float e = asrc[ssrc[o + j]] + ad;
        e = e > 0.f ? e : 0.2f * e;
        m = fmaxf(m, e);
    }
#pragma unroll
    for (int t = 32; t; t >>= 1) m = fmaxf(m, __shfl_xor(m, t));
    float z = 0.f;
    for (int j = lane; j < n; j += 64) {
        float e = asrc[ssrc[o + j]] + ad;
        e = e > 0.f ? e : 0.2f * e;
        z += expf(e - m);
    }
#pragma unroll
    for (int t = 32; t; t >>= 1) z += __shfl_xor(z, t);
    float zinv = 1.0f / (z + 1e-16f);

    float4 acc = {0.f, 0.f, 0.f, 0.f};
    int j = 0;
    for (; j + 2 <= n; j += 2) {
        int s0 = ssrc[o + j], s1 = ssrc[o + j + 1];
        const ushort4 h0 = *reinterpret_cast<const ushort4*>(&h[(long)s0 * HID + lane * 4]);
        const ushort4 h1 = *reinterpret_cast<const ushort4*>(&h[(long)s1 * HID + lane * 4]);
        float e0 = asrc[s0] + ad; e0 = e0 > 0.f ? e0 : 0.2f * e0;
        float e1 = asrc[s1] + ad; e1 = e1 > 0.f ? e1 : 0.2f * e1;
        float a0 = expf(e0 - m) * zinv;
        float a1 = expf(e1 - m) * zinv;
        acc.x += a0 * bf2f(h0.x) + a1 * bf2f(h1.x);
        acc.y += a0 * bf2f(h0.y) + a1 * bf2f(h1.y);
        acc.z += a0 * bf2f(h0.z) + a1 * bf2f(h1.z);
        acc.w += a0 * bf2f(h0.w) + a1 * bf2f(h1.w);
    }
    if (j < n) {
        int s0 = ssrc[o + j];
        const ushort4 h0 = *reinterpret_cast<const ushort4*>(&h[(long)s0 * HID + lane * 4]);
        float e0 = asrc[s0] + ad; e0 = e0 > 0.f ? e0 : 0.2f * e0;
        float a0 = expf(e0 - m) * zinv;
        acc.x += a0 * bf2f(h0.x); acc.y += a0 * bf2f(h0.y);
        acc.z += a0 * bf2f(h0.z); acc.w += a0 * bf2f(h0.w);
    }
    ushort4 r;
    r.x = (unsigned short)f2bf(acc.x > 0.f ? acc.x : expm1f(acc.x));
    r.y = (unsigned short)f2bf(acc.y > 0.f ? acc.y : expm1f(acc.y));
    r.z = (unsigned short)f2bf(acc.z > 0.f ? acc.z : expm1f(acc.z));
    r.w = (unsigned short)f2bf(acc.w > 0.f ? acc.w : expm1f(acc.w));
    *reinterpret_cast<ushort4*>(&gat2[(long)d * HID + lane * 4]) = r;
}

// ---------------- batchnorm ----------------------------------------------------------------
__global__ void bn_partial(const float* __restrict__ zd, float* __restrict__ s,
                           float* __restrict__ sq) {
    int t = threadIdx.x;
    float a = 0.f, b = 0.f;
    int r0 = blockIdx.x * 128;
    for (int r = r0; r < r0 + 128; ++r) {
        float v = zd[(long)r * HID + t];
        a += v;
        b += v * v;
    }
    atomicAdd(&s[t], a);
    atomicAdd(&sq[t], b);
}

__global__ void bn_finalize(const float* __restrict__ s, const float* __restrict__ sq,
                            const float* __restrict__ gamma, const float* __restrict__ beta,
                            float* __restrict__ scale, float* __restrict__ shift) {
    int t = threadIdx.x;
    float mean = s[t] / (float)NN;
    float var  = sq[t] / (float)NN - mean * mean;
    float sc   = gamma[t] * rsqrtf(var + 1e-5f);
    scale[t] = sc;
    shift[t] = beta[t] - mean * sc;
}

__global__ void bn_apply_elu_bf(const float* __restrict__ zd, const float* __restrict__ scale,
                                const float* __restrict__ shift, unsigned short* __restrict__ zb) {
    for (long i = (long)blockIdx.x * blockDim.x + threadIdx.x; i < (long)NN * HID;
         i += (long)gridDim.x * blockDim.x) {
        int c = (int)(i & 255);
        float v = zd[i] * scale[c] + shift[c];
        v = v > 0.f ? v : expm1f(v);
        zb[i] = (unsigned short)f2bf(v);
    }
}

// ---------------- fused readout-norm + discriminator ---------------------------------------
__global__ void readout_disc(const float* __restrict__ vsum_part,
                             const float* __restrict__ rowsum_part,
                             const float* __restrict__ h2f,
                             const float* __restrict__ W, const float* __restrict__ b,
                             float* __restrict__ ret, float* __restrict__ reta) {
    __shared__ float gg[128];
    int r = blockIdx.x, t = threadIdx.x;
    float rs = 0.f, v = 0.f;
#pragma unroll
    for (int kc = 0; kc < 4; ++kc) {
        rs += rowsum_part[(long)kc * NN + r];
        v  += vsum_part[((long)kc * NN + r) * 128 + t];
    }
    v /= rs;
    int w = t >> 6, lane = t & 63;
    float sq = v * v;
#pragma unroll
    for (int off = 32; off > 0; off >>= 1) sq += __shfl_xor(sq, off);
    float nrm = fmaxf(sqrtf(sq), 1e-12f);
    gg[t] = 1.0f / (1.0f + expf(-(v / nrm)));
    __syncthreads();
    const float* hp_base = h2f + (w ? 524288 : 0);
    const float* hm_base = h2f + (w ? 0 : 524288);
    float u = 0.f;
#pragma unroll 8
    for (int e = 0; e < 64; ++e) u += W[lane * 64 + e] * gg[w * 64 + e];
    float hp = hp_base[(long)r * 64 + lane];
    float hm = hm_base[(long)r * 64 + lane];
    float t1 = hp * u, t2 = hm * u;
#pragma unroll
    for (int off = 32; off > 0; off >>= 1) {
        t1 += __shfl_xor(t1, off);
        t2 += __shfl_xor(t2, off);
    }
    if (lane == 0) {
        float bb = b[0];
        float* dstp = w ? reta : ret;
        dstp[r * 2]     = t1 + bb;
        dstp[r * 2 + 1] = t2 + bb;
    }
}

// ---------------- driver -------------------------------------------------------------------
extern "C" void kernel_launch(void* const* d_in, const int* in_sizes, int n_in,
                              void* d_out, int out_size, void* d_ws, size_t ws_size,
                              hipStream_t stream) {
    const float* feat    = (const float*)d_in[0];
    const float* feat_a  = (const float*)d_in[1];
    const float* gneigh  = (const float*)d_in[2];
    const float* W1      = (const float*)d_in[3];
    const float* att_src = (const float*)d_in[4];
    const float* att_dst = (const float*)d_in[5];
    const float* W2      = (const float*)d_in[6];
    const float* Wd1     = (const float*)d_in[7];
    const float* bd1     = (const float*)d_in[8];
    const float* gamma   = (const float*)d_in[9];
    const float* beta    = (const float*)d_in[10];
    const float* Wd2     = (const float*)d_in[11];
    const float* bd2     = (const float*)d_in[12];
    const float* disc_W  = (const float*)d_in[13];
    const float* disc_b  = (const float*)d_in[14];
    const int*   eidx    = (const int*)d_in[15];
    const int*   src = eidx;
    const int*   dst = eidx + EE;
    float* out = (float*)d_out;

    // workspace layout (floats)
    float* w = (float*)d_ws;
    unsigned short* h_bf2  = (unsigned short*)w;                   // [2][8192][256] bf16 = 2097152 f
    unsigned short* gat_bf2 = (unsigned short*)(w + 2097152);      // [2][8192][256] bf16 = 2097152 f
    float* zdec    = w + 4194304;                                  // [8192][256] f32 = 2097152 f
    unsigned short* zdec_bf = (unsigned short*)(zdec + 2097152);   // 1048576 f
    float* h2f     = zdec + 2097152 + 1048576;                     // [2][8192][64] = 1048576 f
    unsigned short* h2b = (unsigned short*)(h2f + 1048576);        // [8192][64] bf16 = 262144 f
    unsigned short* HT  = h2b + 524288;                            // [128][8192] bf16 = 524288 f
    float* asrc2   = (float*)(HT + 1048576);                       // 16384
    float* adst2   = asrc2 + 16384;                                // 16384
    float* bnsum   = adst2 + 16384;           // 256
    float* bnsq    = bnsum + 256;             // 256
    float* scale   = bnsq + 256;              // 256
    float* shift   = scale + 256;             // 256
    unsigned short* W1t  = (unsigned short*)(shift + 256);         // 770048 sh
    unsigned short* W2t  = W1t + 770048;                           // 16384 sh
    unsigned short* Wd1t = W2t + 16384;                            // 16384 sh
    unsigned short* Wd2t = Wd1t + 16384;                           // 786432 sh
    int*   ideg    = (int*)(Wd2t + 786432);   // 8192
    int*   ioff    = ideg + 8192;             // 8192
    int*   icur    = ioff + 8192;             // 8192
    int*   issrc   = icur + 8192;             // 262144
    // feat split-K partials: 4 x [16384][256] f32 = 64 MB in the not-yet-written h3 region
    float* part = out + O_H3;                 // 16777216 f <= 24576000 f available
    // readout-phase reuse: h_bf2 + gat_bf2 (dead after w2_gemm) -> vsum partials (16 MB)
    float* vsum_part = w;                     // 4*8192*128 = 4194304 f
    float* rowsum_part = zdec;                // 4*8192 = 32768 f (zdec dead after bn_apply)

    // ---- one-time weight conversions
    cvt_W1t<<<3008, 256, 0, stream>>>(W1, W1t);
    cvt_W2t<<<64, 256, 0, stream>>>(W2, W2t);
    cvt_Wd1t<<<64, 256, 0, stream>>>(Wd1, Wd1t);
    cvt_Wd2t<<<3072, 256, 0, stream>>>(Wd2, Wd2t);

    // ---- CSR build
    hipMemsetAsync(ideg, 0, 8192 * 4, stream);
    deg_count<<<EE / 256, 256, 0, stream>>>(dst, ideg);
    scan_offsets<<<1, 256, 0, stream>>>(ideg, ioff, icur);
    scatter_edges<<<EE / 256, 256, 0, stream>>>(src, dst, icur, issrc);

    // ---- encoder (both passes batched; split-K=4 for occupancy)
    feat_gemm<<<dim3(2, 128, 4), 256, 0, stream>>>(feat, feat_a, W1t, part);
    reduce_cvt4<<<4096, 256, 0, stream>>>(part, h_bf2);
    attn_coeff_bf<<<4096, 256, 0, stream>>>(h_bf2, att_src, att_dst, asrc2, adst2);
    gat_gather<<<4096, 256, 0, stream>>>(issrc, ioff, ideg, asrc2, adst2, h_bf2, gat_bf2);
    w2_gemm<<<dim3(1, 256), 256, 0, stream>>>(gat_bf2, W2t, h2f, h2b, HT, out);

    // ---- decoder: h3 = elu(BN(h2 @ Wd1 + bd1)) @ Wd2 + bd2
    wd1_gemm<<<dim3(4, 128), 256, 0, stream>>>(h2b, Wd1t, bd1, zdec);
    hipMemsetAsync(bnsum, 0, 512 * 4, stream);
    bn_partial<<<64, 256, 0, stream>>>(zdec, bnsum, bnsq);
    bn_finalize<<<1, 256, 0, stream>>>(bnsum, bnsq, gamma, beta, scale, shift);
    bn_apply_elu_bf<<<2048, 256, 0, stream>>>(zdec, scale, shift, zdec_bf);
    wd2_gemm<<<dim3(24, 64), 256, 0, stream>>>(zdec_bf, Wd2t, bd2, out + O_H3);

    // ---- readout + discriminator
    readout_mfma2<<<dim3(128, 4), 256, 0, stream>>>(gneigh, HT, vsum_part, rowsum_part);
    readout_disc<<<8192, 128, 0, stream>>>(vsum_part, rowsum_part, h2f, disc_W, disc_b,
                                           out + O_RET, out + O_RETA);
}